// Round 1
// baseline (917.862 us; speedup 1.0000x reference)
//
#include <hip/hip_runtime.h>
#include <math.h>

// Problem constants
#define NG   12      // groups
#define NH   8       // heads per group
#define CIN  64
#define CQK  32
#define CVAL 32
#define COUT 64
#define NB   2
#define NN   512
#define NROWS (NB * NN)     // 1024
#define GHH  (NG * NH)      // 96 heads
#define DIN  (NG * CIN)     // 768
#define DQK  (GHH * CQK)    // 3072
#define DOUT (NG * COUT)    // 768

// ---------------------------------------------------------------------------
// Kernel 1: block-circulant QKV projection.
// out[b,n, hg*256 + o] = sum_g sum_i x[b,n, g*64+i] * W[(g-hg)%12][o][i]
// 128x128 output tile per block, 8x8 micro-tile per thread, LDS i-major.
// ---------------------------------------------------------------------------
__global__ __launch_bounds__(256) void qkv_proj_kernel(
    const float* __restrict__ x,
    const float* __restrict__ Wq,
    const float* __restrict__ Wk,
    const float* __restrict__ Wv,
    float* __restrict__ qo,
    float* __restrict__ ko,
    float* __restrict__ vo)
{
    __shared__ float As[64][128];   // As[i][r] = x[m0+r][g*64+i]
    __shared__ float Bs[64][128];   // Bs[i][o] = W[gp][o0+o][i]
    const int z = blockIdx.z;
    const float* __restrict__ W = (z == 0) ? Wq : (z == 1) ? Wk : Wv;
    float* __restrict__ out = (z == 0) ? qo : (z == 1) ? ko : vo;
    const int m0 = blockIdx.y * 128;
    const int c0 = blockIdx.x * 128;
    const int hg = c0 >> 8;          // output group (co = 256)
    const int o0 = c0 & 255;
    const int tid = threadIdx.x;
    const int tx = tid & 15;
    const int ty = tid >> 4;
    const int lr = tid >> 1;         // 0..127: row (A) / out-channel (B)
    const int lc = (tid & 1) * 32;   // i-offset

    float acc[8][8];
    #pragma unroll
    for (int i = 0; i < 8; ++i)
        #pragma unroll
        for (int j = 0; j < 8; ++j) acc[i][j] = 0.f;

    for (int g = 0; g < NG; ++g) {
        int gp = g - hg; if (gp < 0) gp += NG;
        const float* srcA = x + (size_t)(m0 + lr) * DIN + g * 64 + lc;
        const float* srcB = W + (size_t)gp * (256 * 64) + (size_t)(o0 + lr) * 64 + lc;
        #pragma unroll
        for (int u = 0; u < 8; ++u) {
            float4 t = *(const float4*)(srcA + 4 * u);
            int i0 = lc + 4 * u;
            As[i0][lr] = t.x; As[i0 + 1][lr] = t.y; As[i0 + 2][lr] = t.z; As[i0 + 3][lr] = t.w;
        }
        #pragma unroll
        for (int u = 0; u < 8; ++u) {
            float4 t = *(const float4*)(srcB + 4 * u);
            int i0 = lc + 4 * u;
            Bs[i0][lr] = t.x; Bs[i0 + 1][lr] = t.y; Bs[i0 + 2][lr] = t.z; Bs[i0 + 3][lr] = t.w;
        }
        __syncthreads();
        #pragma unroll 4
        for (int i = 0; i < 64; ++i) {
            float a[8], w[8];
            *(float4*)(a)     = *(const float4*)&As[i][ty * 8];
            *(float4*)(a + 4) = *(const float4*)&As[i][ty * 8 + 4];
            *(float4*)(w)     = *(const float4*)&Bs[i][tx * 8];
            *(float4*)(w + 4) = *(const float4*)&Bs[i][tx * 8 + 4];
            #pragma unroll
            for (int rr = 0; rr < 8; ++rr)
                #pragma unroll
                for (int cc = 0; cc < 8; ++cc)
                    acc[rr][cc] = fmaf(a[rr], w[cc], acc[rr][cc]);
        }
        __syncthreads();
    }
    #pragma unroll
    for (int rr = 0; rr < 8; ++rr) {
        float* dst = out + (size_t)(m0 + ty * 8 + rr) * DQK + c0 + tx * 8;
        *(float4*)dst       = make_float4(acc[rr][0], acc[rr][1], acc[rr][2], acc[rr][3]);
        *(float4*)(dst + 4) = make_float4(acc[rr][4], acc[rr][5], acc[rr][6], acc[rr][7]);
    }
}

// ---------------------------------------------------------------------------
// Kernel 2: RMSNorm + fused sequence-rope + platonic-rope for q AND k.
// Both ropes rotate the same (even,odd) pairs -> angles add; one sincos per
// (b,n,g,h,f) shared between q and k.
// ---------------------------------------------------------------------------
__global__ __launch_bounds__(256) void norm_rope_kernel(
    float* __restrict__ q, float* __restrict__ k,
    const float* __restrict__ coords,
    const int* __restrict__ seq,
    const float* __restrict__ qw,
    const float* __restrict__ kw,
    const float* __restrict__ pf)
{
    const int hid = blockIdx.x * 256 + threadIdx.x;   // [0, 98304)
    const int gh = hid % GHH;
    const int bn = hid / GHH;
    const int g = gh >> 3;
    const int h = gh & 7;
    float* qp = q + (size_t)hid * CQK;
    float* kp = k + (size_t)hid * CQK;
    float xq[CQK], xk[CQK];
    #pragma unroll
    for (int u = 0; u < 8; ++u) *(float4*)(xq + 4 * u) = *(const float4*)(qp + 4 * u);
    #pragma unroll
    for (int u = 0; u < 8; ++u) *(float4*)(xk + 4 * u) = *(const float4*)(kp + 4 * u);

    float sq = 0.f, sk = 0.f;
    #pragma unroll
    for (int c = 0; c < CQK; ++c) { sq = fmaf(xq[c], xq[c], sq); sk = fmaf(xk[c], xk[c], sk); }
    const float eps = 1.1920928955078125e-07f;   // finfo(float32).eps
    const float invq = rsqrtf(sq * (1.f / CQK) + eps);
    const float invk = rsqrtf(sk * (1.f / CQK) + eps);
    #pragma unroll
    for (int c = 0; c < CQK; ++c) { xq[c] *= invq * qw[c]; xk[c] *= invk * kw[c]; }

    const float pos = (float)seq[bn];
    const float cx = coords[bn * 3 + 0], cy = coords[bn * 3 + 1], cz = coords[bn * 3 + 2];
    float sg, cg;
    sincosf((float)g * 0.5235987755982988f, &sg, &cg);   // 2*pi*g/12
    const float u0 = cg * cx + sg * cy;   // (R[g]^T coords)
    const float u1 = cg * cy - sg * cx;
    const float u2 = cz;

    #pragma unroll
    for (int f = 0; f < 16; ++f) {
        // inv_freq = 10000^(-f/16) = 2^(-f*log2(10000)/16)
        const float invf = exp2f(-(float)f * 0.8304820237218405f);
        const float* fr = pf + ((size_t)h * 16 + f) * 3;
        const float ang = fmaf(pos, invf, u0 * fr[0] + u1 * fr[1] + u2 * fr[2]);
        float sn, cs;
        sincosf(ang, &sn, &cs);
        float a1 = xq[2 * f], a2 = xq[2 * f + 1];
        xq[2 * f]     = a1 * cs - a2 * sn;
        xq[2 * f + 1] = a1 * sn + a2 * cs;
        float b1 = xk[2 * f], b2 = xk[2 * f + 1];
        xk[2 * f]     = b1 * cs - b2 * sn;
        xk[2 * f + 1] = b1 * sn + b2 * cs;
    }
    #pragma unroll
    for (int u = 0; u < 8; ++u) *(float4*)(qp + 4 * u) = *(const float4*)(xq + 4 * u);
    #pragma unroll
    for (int u = 0; u < 8; ++u) *(float4*)(kp + 4 * u) = *(const float4*)(xk + 4 * u);
}

// ---------------------------------------------------------------------------
// Kernel 3: attention. One thread per q-row; online softmax over K tiles of
// 32. K/V addresses are wave-uniform -> compiler can use scalar (s_load)
// reads; FMA takes the K/V value as the SGPR operand.
// ---------------------------------------------------------------------------
__global__ __launch_bounds__(256) void attn_kernel(
    const float* __restrict__ q,
    const float* __restrict__ k,
    const float* __restrict__ v,
    float* __restrict__ out)
{
    const int b = blockIdx.z;
    const int gh = blockIdx.y;
    const int r = blockIdx.x * 256 + threadIdx.x;
    const size_t headoff = (size_t)b * NN * DQK + (size_t)gh * CQK;
    const float* qp = q + headoff + (size_t)r * DQK;
    float qr[CQK];
    #pragma unroll
    for (int u = 0; u < 8; ++u) *(float4*)(qr + 4 * u) = *(const float4*)(qp + 4 * u);
    const float scale = 0.17677669529663687f;  // 1/sqrt(32)
    #pragma unroll
    for (int c = 0; c < CQK; ++c) qr[c] *= scale;

    float m = -3.0e38f, l = 0.f;
    float acc[CVAL];
    #pragma unroll
    for (int c = 0; c < CVAL; ++c) acc[c] = 0.f;

    const float* kb = k + headoff;
    const float* vb = v + headoff;
    for (int j0 = 0; j0 < NN; j0 += 32) {
        float s[32];
        #pragma unroll
        for (int jj = 0; jj < 32; ++jj) {
            const float* kr = kb + (size_t)(j0 + jj) * DQK;   // uniform address
            float d0 = 0.f, d1 = 0.f, d2 = 0.f, d3 = 0.f;
            #pragma unroll
            for (int c = 0; c < CQK; c += 4) {
                d0 = fmaf(qr[c + 0], kr[c + 0], d0);
                d1 = fmaf(qr[c + 1], kr[c + 1], d1);
                d2 = fmaf(qr[c + 2], kr[c + 2], d2);
                d3 = fmaf(qr[c + 3], kr[c + 3], d3);
            }
            s[jj] = (d0 + d1) + (d2 + d3);
        }
        float tm = s[0];
        #pragma unroll
        for (int jj = 1; jj < 32; ++jj) tm = fmaxf(tm, s[jj]);
        const float mnew = fmaxf(m, tm);
        const float corr = __expf(m - mnew);   // first tile: exp(-huge)=0
        l *= corr;
        #pragma unroll
        for (int c = 0; c < CVAL; ++c) acc[c] *= corr;
        #pragma unroll
        for (int jj = 0; jj < 32; ++jj) {
            const float p = __expf(s[jj] - mnew);
            l += p;
            const float* vr = vb + (size_t)(j0 + jj) * DQK;   // uniform address
            #pragma unroll
            for (int c = 0; c < CVAL; ++c) acc[c] = fmaf(p, vr[c], acc[c]);
        }
        m = mnew;
    }
    const float inv = 1.f / l;
    float* op = out + headoff + (size_t)r * DQK;
    #pragma unroll
    for (int u = 0; u < 8; ++u)
        *(float4*)(op + 4 * u) = make_float4(acc[4 * u] * inv, acc[4 * u + 1] * inv,
                                             acc[4 * u + 2] * inv, acc[4 * u + 3] * inv);
}

// ---------------------------------------------------------------------------
// Kernel 4: block-circulant output projection.
// out[b,n, h*64 + o] = sum_g sum_i attn[b,n, g*256+i] * Wo[(g-h)%12][o][i]
// 64x64 tile per block, 4x4 micro-tile per thread.
// ---------------------------------------------------------------------------
__global__ __launch_bounds__(256) void oproj_kernel(
    const float* __restrict__ a,
    const float* __restrict__ Wo,
    float* __restrict__ out)
{
    __shared__ float As[64][64];   // As[i][r]
    __shared__ float Bs[64][64];   // Bs[i][o]
    const int h = blockIdx.x;       // 0..11
    const int m0 = blockIdx.y * 64;
    const int tid = threadIdx.x;
    const int tx = tid & 15;
    const int ty = tid >> 4;
    const int lr = tid >> 2;          // 0..63
    const int lc = (tid & 3) * 16;    // 16 floats per thread per tile

    float acc[4][4];
    #pragma unroll
    for (int i = 0; i < 4; ++i)
        #pragma unroll
        for (int j = 0; j < 4; ++j) acc[i][j] = 0.f;

    for (int kb = 0; kb < 48; ++kb) {
        const int g = kb >> 2;
        const int ic = (kb & 3) * 64;
        int gp = g - h; if (gp < 0) gp += NG;
        const float* srcA = a + (size_t)(m0 + lr) * DQK + g * 256 + ic + lc;
        const float* srcB = Wo + (size_t)gp * (COUT * 256) + (size_t)lr * 256 + ic + lc;
        #pragma unroll
        for (int u = 0; u < 4; ++u) {
            float4 t = *(const float4*)(srcA + 4 * u);
            int i0 = lc + 4 * u;
            As[i0][lr] = t.x; As[i0 + 1][lr] = t.y; As[i0 + 2][lr] = t.z; As[i0 + 3][lr] = t.w;
        }
        #pragma unroll
        for (int u = 0; u < 4; ++u) {
            float4 t = *(const float4*)(srcB + 4 * u);
            int i0 = lc + 4 * u;
            Bs[i0][lr] = t.x; Bs[i0 + 1][lr] = t.y; Bs[i0 + 2][lr] = t.z; Bs[i0 + 3][lr] = t.w;
        }
        __syncthreads();
        #pragma unroll 8
        for (int i = 0; i < 64; ++i) {
            float av[4], wv[4];
            *(float4*)av = *(const float4*)&As[i][ty * 4];
            *(float4*)wv = *(const float4*)&Bs[i][tx * 4];
            #pragma unroll
            for (int rr = 0; rr < 4; ++rr)
                #pragma unroll
                for (int cc = 0; cc < 4; ++cc)
                    acc[rr][cc] = fmaf(av[rr], wv[cc], acc[rr][cc]);
        }
        __syncthreads();
    }
    #pragma unroll
    for (int rr = 0; rr < 4; ++rr) {
        float* dst = out + (size_t)(m0 + ty * 4 + rr) * DOUT + h * 64 + tx * 4;
        *(float4*)dst = make_float4(acc[rr][0], acc[rr][1], acc[rr][2], acc[rr][3]);
    }
}

// ---------------------------------------------------------------------------
extern "C" void kernel_launch(void* const* d_in, const int* in_sizes, int n_in,
                              void* d_out, int out_size, void* d_ws, size_t ws_size,
                              hipStream_t stream)
{
    const float* feat   = (const float*)d_in[0];
    const float* coords = (const float*)d_in[1];
    const float* Wq     = (const float*)d_in[2];
    const float* Wk     = (const float*)d_in[3];
    const float* Wv     = (const float*)d_in[4];
    const float* Wo     = (const float*)d_in[5];
    const float* qw     = (const float*)d_in[6];
    const float* kw     = (const float*)d_in[7];
    const float* pf     = (const float*)d_in[8];
    const int*   seq    = (const int*)d_in[9];

    // workspace: q, k, v, attn_out  (each 1024*3072 fp32 = 12.58 MB; 50.3 MB total)
    float* q  = (float*)d_ws;
    float* k  = q + (size_t)NROWS * DQK;
    float* v  = k + (size_t)NROWS * DQK;
    float* ao = v + (size_t)NROWS * DQK;

    qkv_proj_kernel<<<dim3(24, 8, 3), 256, 0, stream>>>(feat, Wq, Wk, Wv, q, k, v);
    norm_rope_kernel<<<dim3(384), 256, 0, stream>>>(q, k, coords, seq, qw, kw, pf);
    attn_kernel<<<dim3(2, 96, 2), 256, 0, stream>>>(q, k, v, ao);
    oproj_kernel<<<dim3(12, 16), 256, 0, stream>>>(ao, Wo, (float*)d_out);
}

// Round 2
// 592.308 us; speedup vs baseline: 1.5496x; 1.5496x over previous
//
#include <hip/hip_runtime.h>
#include <math.h>

// Problem constants
#define NG   12      // groups
#define NH   8       // heads per group
#define CIN  64
#define CQK  32
#define CVAL 32
#define COUT 64
#define NB   2
#define NN   512
#define NROWS (NB * NN)     // 1024
#define GHH  (NG * NH)      // 96 heads
#define DIN  (NG * CIN)     // 768
#define DQK  (GHH * CQK)    // 3072
#define DOUT (NG * COUT)    // 768

// ---------------------------------------------------------------------------
// Kernel 1: block-circulant QKV projection.
// out[b,n, hg*256 + o] = sum_g sum_i x[b,n, g*64+i] * W[(g-hg)%12][o][i]
// 128x128 output tile per block, 8x8 micro-tile per thread, LDS i-major.
// ---------------------------------------------------------------------------
__global__ __launch_bounds__(256) void qkv_proj_kernel(
    const float* __restrict__ x,
    const float* __restrict__ Wq,
    const float* __restrict__ Wk,
    const float* __restrict__ Wv,
    float* __restrict__ qo,
    float* __restrict__ ko,
    float* __restrict__ vo)
{
    __shared__ float As[64][128];   // As[i][r] = x[m0+r][g*64+i]
    __shared__ float Bs[64][128];   // Bs[i][o] = W[gp][o0+o][i]
    const int z = blockIdx.z;
    const float* __restrict__ W = (z == 0) ? Wq : (z == 1) ? Wk : Wv;
    float* __restrict__ out = (z == 0) ? qo : (z == 1) ? ko : vo;
    const int m0 = blockIdx.y * 128;
    const int c0 = blockIdx.x * 128;
    const int hg = c0 >> 8;          // output group (co = 256)
    const int o0 = c0 & 255;
    const int tid = threadIdx.x;
    const int tx = tid & 15;
    const int ty = tid >> 4;
    const int lr = tid >> 1;         // 0..127: row (A) / out-channel (B)
    const int lc = (tid & 1) * 32;   // i-offset

    float acc[8][8];
    #pragma unroll
    for (int i = 0; i < 8; ++i)
        #pragma unroll
        for (int j = 0; j < 8; ++j) acc[i][j] = 0.f;

    for (int g = 0; g < NG; ++g) {
        int gp = g - hg; if (gp < 0) gp += NG;
        const float* srcA = x + (size_t)(m0 + lr) * DIN + g * 64 + lc;
        const float* srcB = W + (size_t)gp * (256 * 64) + (size_t)(o0 + lr) * 64 + lc;
        #pragma unroll
        for (int u = 0; u < 8; ++u) {
            float4 t = *(const float4*)(srcA + 4 * u);
            int i0 = lc + 4 * u;
            As[i0][lr] = t.x; As[i0 + 1][lr] = t.y; As[i0 + 2][lr] = t.z; As[i0 + 3][lr] = t.w;
        }
        #pragma unroll
        for (int u = 0; u < 8; ++u) {
            float4 t = *(const float4*)(srcB + 4 * u);
            int i0 = lc + 4 * u;
            Bs[i0][lr] = t.x; Bs[i0 + 1][lr] = t.y; Bs[i0 + 2][lr] = t.z; Bs[i0 + 3][lr] = t.w;
        }
        __syncthreads();
        #pragma unroll 4
        for (int i = 0; i < 64; ++i) {
            float a[8], w[8];
            *(float4*)(a)     = *(const float4*)&As[i][ty * 8];
            *(float4*)(a + 4) = *(const float4*)&As[i][ty * 8 + 4];
            *(float4*)(w)     = *(const float4*)&Bs[i][tx * 8];
            *(float4*)(w + 4) = *(const float4*)&Bs[i][tx * 8 + 4];
            #pragma unroll
            for (int rr = 0; rr < 8; ++rr)
                #pragma unroll
                for (int cc = 0; cc < 8; ++cc)
                    acc[rr][cc] = fmaf(a[rr], w[cc], acc[rr][cc]);
        }
        __syncthreads();
    }
    #pragma unroll
    for (int rr = 0; rr < 8; ++rr) {
        float* dst = out + (size_t)(m0 + ty * 8 + rr) * DQK + c0 + tx * 8;
        *(float4*)dst       = make_float4(acc[rr][0], acc[rr][1], acc[rr][2], acc[rr][3]);
        *(float4*)(dst + 4) = make_float4(acc[rr][4], acc[rr][5], acc[rr][6], acc[rr][7]);
    }
}

// ---------------------------------------------------------------------------
// Kernel 2: RMSNorm + fused sequence-rope + platonic-rope for q AND k.
// ---------------------------------------------------------------------------
__global__ __launch_bounds__(256) void norm_rope_kernel(
    float* __restrict__ q, float* __restrict__ k,
    const float* __restrict__ coords,
    const int* __restrict__ seq,
    const float* __restrict__ qw,
    const float* __restrict__ kw,
    const float* __restrict__ pf)
{
    const int hid = blockIdx.x * 256 + threadIdx.x;   // [0, 98304)
    const int gh = hid % GHH;
    const int bn = hid / GHH;
    const int g = gh >> 3;
    const int h = gh & 7;
    float* qp = q + (size_t)hid * CQK;
    float* kp = k + (size_t)hid * CQK;
    float xq[CQK], xk[CQK];
    #pragma unroll
    for (int u = 0; u < 8; ++u) *(float4*)(xq + 4 * u) = *(const float4*)(qp + 4 * u);
    #pragma unroll
    for (int u = 0; u < 8; ++u) *(float4*)(xk + 4 * u) = *(const float4*)(kp + 4 * u);

    float sq = 0.f, sk = 0.f;
    #pragma unroll
    for (int c = 0; c < CQK; ++c) { sq = fmaf(xq[c], xq[c], sq); sk = fmaf(xk[c], xk[c], sk); }
    const float eps = 1.1920928955078125e-07f;   // finfo(float32).eps
    const float invq = rsqrtf(sq * (1.f / CQK) + eps);
    const float invk = rsqrtf(sk * (1.f / CQK) + eps);
    #pragma unroll
    for (int c = 0; c < CQK; ++c) { xq[c] *= invq * qw[c]; xk[c] *= invk * kw[c]; }

    const float pos = (float)seq[bn];
    const float cx = coords[bn * 3 + 0], cy = coords[bn * 3 + 1], cz = coords[bn * 3 + 2];
    float sg, cg;
    sincosf((float)g * 0.5235987755982988f, &sg, &cg);   // 2*pi*g/12
    const float u0 = cg * cx + sg * cy;   // (R[g]^T coords)
    const float u1 = cg * cy - sg * cx;
    const float u2 = cz;

    #pragma unroll
    for (int f = 0; f < 16; ++f) {
        const float invf = exp2f(-(float)f * 0.8304820237218405f);
        const float* fr = pf + ((size_t)h * 16 + f) * 3;
        const float ang = fmaf(pos, invf, u0 * fr[0] + u1 * fr[1] + u2 * fr[2]);
        float sn, cs;
        sincosf(ang, &sn, &cs);
        float a1 = xq[2 * f], a2 = xq[2 * f + 1];
        xq[2 * f]     = a1 * cs - a2 * sn;
        xq[2 * f + 1] = a1 * sn + a2 * cs;
        float b1 = xk[2 * f], b2 = xk[2 * f + 1];
        xk[2 * f]     = b1 * cs - b2 * sn;
        xk[2 * f + 1] = b1 * sn + b2 * cs;
    }
    #pragma unroll
    for (int u = 0; u < 8; ++u) *(float4*)(qp + 4 * u) = *(const float4*)(xq + 4 * u);
    #pragma unroll
    for (int u = 0; u < 8; ++u) *(float4*)(kp + 4 * u) = *(const float4*)(xk + 4 * u);
}

// ---------------------------------------------------------------------------
// Kernel 3 (REWRITTEN): attention, LDS-staged K/V.
// One block per (b, head). 256 threads; thread owns q-rows {tid, tid+256}.
// K/V tiles of 128 rows staged in LDS (32 KB). Inner loop: broadcast
// ds_read_b128 of K/V row + register FMAs; each 16B LDS read feeds 8 FMAs
// (4 c-values x 2 q-rows). Online softmax in chunks of 16 keys.
// ---------------------------------------------------------------------------
__global__ __launch_bounds__(256, 1) void attn_kernel(
    const float* __restrict__ q,
    const float* __restrict__ k,
    const float* __restrict__ v,
    float* __restrict__ out)
{
    __shared__ float Ks[128][CQK];
    __shared__ float Vs[128][CVAL];
    const int gh = blockIdx.x;
    const int b  = blockIdx.y;
    const size_t headoff = (size_t)b * NN * DQK + (size_t)gh * CQK;
    const int tid = threadIdx.x;
    const int r0 = tid;          // q row 0
    const int r1 = tid + 256;    // q row 1

    const float scale = 0.17677669529663687f;  // 1/sqrt(32)
    float qr[2][CQK];
    {
        const float* qp0 = q + headoff + (size_t)r0 * DQK;
        const float* qp1 = q + headoff + (size_t)r1 * DQK;
        #pragma unroll
        for (int u = 0; u < 8; ++u) {
            float4 t0 = *(const float4*)(qp0 + 4 * u);
            float4 t1 = *(const float4*)(qp1 + 4 * u);
            qr[0][4*u] = t0.x * scale; qr[0][4*u+1] = t0.y * scale;
            qr[0][4*u+2] = t0.z * scale; qr[0][4*u+3] = t0.w * scale;
            qr[1][4*u] = t1.x * scale; qr[1][4*u+1] = t1.y * scale;
            qr[1][4*u+2] = t1.z * scale; qr[1][4*u+3] = t1.w * scale;
        }
    }

    float m0v = -3.0e38f, m1v = -3.0e38f, l0 = 0.f, l1 = 0.f;
    float acc[2][CVAL];
    #pragma unroll
    for (int c = 0; c < CVAL; ++c) { acc[0][c] = 0.f; acc[1][c] = 0.f; }

    const int lr = tid >> 1;          // 0..127 : tile row this thread stages
    const int lc = (tid & 1) * 16;    // half-row offset

    for (int j0 = 0; j0 < NN; j0 += 128) {
        // ---- stage K/V tile ----
        const float* kp = k + headoff + (size_t)(j0 + lr) * DQK + lc;
        const float* vp = v + headoff + (size_t)(j0 + lr) * DQK + lc;
        #pragma unroll
        for (int u = 0; u < 4; ++u)
            *(float4*)&Ks[lr][lc + 4 * u] = *(const float4*)(kp + 4 * u);
        #pragma unroll
        for (int u = 0; u < 4; ++u)
            *(float4*)&Vs[lr][lc + 4 * u] = *(const float4*)(vp + 4 * u);
        __syncthreads();

        // ---- process in chunks of 16 keys ----
        for (int jc = 0; jc < 128; jc += 16) {
            float s[2][16];
            #pragma unroll
            for (int jj = 0; jj < 16; ++jj) {
                float a0 = 0.f, a1 = 0.f, b0 = 0.f, b1 = 0.f;
                #pragma unroll
                for (int c = 0; c < CQK; c += 4) {
                    float4 kv = *(const float4*)&Ks[jc + jj][c];
                    a0 = fmaf(qr[0][c + 0], kv.x, a0);
                    a1 = fmaf(qr[0][c + 1], kv.y, a1);
                    a0 = fmaf(qr[0][c + 2], kv.z, a0);
                    a1 = fmaf(qr[0][c + 3], kv.w, a1);
                    b0 = fmaf(qr[1][c + 0], kv.x, b0);
                    b1 = fmaf(qr[1][c + 1], kv.y, b1);
                    b0 = fmaf(qr[1][c + 2], kv.z, b0);
                    b1 = fmaf(qr[1][c + 3], kv.w, b1);
                }
                s[0][jj] = a0 + a1;
                s[1][jj] = b0 + b1;
            }
            float tm0 = s[0][0], tm1 = s[1][0];
            #pragma unroll
            for (int jj = 1; jj < 16; ++jj) {
                tm0 = fmaxf(tm0, s[0][jj]);
                tm1 = fmaxf(tm1, s[1][jj]);
            }
            const float mn0 = fmaxf(m0v, tm0);
            const float mn1 = fmaxf(m1v, tm1);
            const float cr0 = __expf(m0v - mn0);
            const float cr1 = __expf(m1v - mn1);
            l0 *= cr0; l1 *= cr1;
            #pragma unroll
            for (int c = 0; c < CVAL; ++c) { acc[0][c] *= cr0; acc[1][c] *= cr1; }
            #pragma unroll
            for (int jj = 0; jj < 16; ++jj) {
                const float p0 = __expf(s[0][jj] - mn0);
                const float p1 = __expf(s[1][jj] - mn1);
                l0 += p0; l1 += p1;
                #pragma unroll
                for (int c = 0; c < CVAL; c += 4) {
                    float4 vv = *(const float4*)&Vs[jc + jj][c];
                    acc[0][c + 0] = fmaf(p0, vv.x, acc[0][c + 0]);
                    acc[0][c + 1] = fmaf(p0, vv.y, acc[0][c + 1]);
                    acc[0][c + 2] = fmaf(p0, vv.z, acc[0][c + 2]);
                    acc[0][c + 3] = fmaf(p0, vv.w, acc[0][c + 3]);
                    acc[1][c + 0] = fmaf(p1, vv.x, acc[1][c + 0]);
                    acc[1][c + 1] = fmaf(p1, vv.y, acc[1][c + 1]);
                    acc[1][c + 2] = fmaf(p1, vv.z, acc[1][c + 2]);
                    acc[1][c + 3] = fmaf(p1, vv.w, acc[1][c + 3]);
                }
            }
            m0v = mn0; m1v = mn1;
        }
        __syncthreads();
    }

    const float inv0 = 1.f / l0;
    const float inv1 = 1.f / l1;
    float* op0 = out + headoff + (size_t)r0 * DQK;
    float* op1 = out + headoff + (size_t)r1 * DQK;
    #pragma unroll
    for (int u = 0; u < 8; ++u) {
        *(float4*)(op0 + 4 * u) = make_float4(acc[0][4*u] * inv0, acc[0][4*u+1] * inv0,
                                              acc[0][4*u+2] * inv0, acc[0][4*u+3] * inv0);
        *(float4*)(op1 + 4 * u) = make_float4(acc[1][4*u] * inv1, acc[1][4*u+1] * inv1,
                                              acc[1][4*u+2] * inv1, acc[1][4*u+3] * inv1);
    }
}

// ---------------------------------------------------------------------------
// Kernel 4: block-circulant output projection.
// ---------------------------------------------------------------------------
__global__ __launch_bounds__(256) void oproj_kernel(
    const float* __restrict__ a,
    const float* __restrict__ Wo,
    float* __restrict__ out)
{
    __shared__ float As[64][64];   // As[i][r]
    __shared__ float Bs[64][64];   // Bs[i][o]
    const int h = blockIdx.x;       // 0..11
    const int m0 = blockIdx.y * 64;
    const int tid = threadIdx.x;
    const int tx = tid & 15;
    const int ty = tid >> 4;
    const int lr = tid >> 2;          // 0..63
    const int lc = (tid & 3) * 16;    // 16 floats per thread per tile

    float acc[4][4];
    #pragma unroll
    for (int i = 0; i < 4; ++i)
        #pragma unroll
        for (int j = 0; j < 4; ++j) acc[i][j] = 0.f;

    for (int kb = 0; kb < 48; ++kb) {
        const int g = kb >> 2;
        const int ic = (kb & 3) * 64;
        int gp = g - h; if (gp < 0) gp += NG;
        const float* srcA = a + (size_t)(m0 + lr) * DQK + g * 256 + ic + lc;
        const float* srcB = Wo + (size_t)gp * (COUT * 256) + (size_t)lr * 256 + ic + lc;
        #pragma unroll
        for (int u = 0; u < 4; ++u) {
            float4 t = *(const float4*)(srcA + 4 * u);
            int i0 = lc + 4 * u;
            As[i0][lr] = t.x; As[i0 + 1][lr] = t.y; As[i0 + 2][lr] = t.z; As[i0 + 3][lr] = t.w;
        }
        #pragma unroll
        for (int u = 0; u < 4; ++u) {
            float4 t = *(const float4*)(srcB + 4 * u);
            int i0 = lc + 4 * u;
            Bs[i0][lr] = t.x; Bs[i0 + 1][lr] = t.y; Bs[i0 + 2][lr] = t.z; Bs[i0 + 3][lr] = t.w;
        }
        __syncthreads();
        #pragma unroll 8
        for (int i = 0; i < 64; ++i) {
            float av[4], wv[4];
            *(float4*)av = *(const float4*)&As[i][ty * 4];
            *(float4*)wv = *(const float4*)&Bs[i][tx * 4];
            #pragma unroll
            for (int rr = 0; rr < 4; ++rr)
                #pragma unroll
                for (int cc = 0; cc < 4; ++cc)
                    acc[rr][cc] = fmaf(av[rr], wv[cc], acc[rr][cc]);
        }
        __syncthreads();
    }
    #pragma unroll
    for (int rr = 0; rr < 4; ++rr) {
        float* dst = out + (size_t)(m0 + ty * 4 + rr) * DOUT + h * 64 + tx * 4;
        *(float4*)dst = make_float4(acc[rr][0], acc[rr][1], acc[rr][2], acc[rr][3]);
    }
}

// ---------------------------------------------------------------------------
extern "C" void kernel_launch(void* const* d_in, const int* in_sizes, int n_in,
                              void* d_out, int out_size, void* d_ws, size_t ws_size,
                              hipStream_t stream)
{
    const float* feat   = (const float*)d_in[0];
    const float* coords = (const float*)d_in[1];
    const float* Wq     = (const float*)d_in[2];
    const float* Wk     = (const float*)d_in[3];
    const float* Wv     = (const float*)d_in[4];
    const float* Wo     = (const float*)d_in[5];
    const float* qw     = (const float*)d_in[6];
    const float* kw     = (const float*)d_in[7];
    const float* pf     = (const float*)d_in[8];
    const int*   seq    = (const int*)d_in[9];

    float* q  = (float*)d_ws;
    float* k  = q + (size_t)NROWS * DQK;
    float* v  = k + (size_t)NROWS * DQK;
    float* ao = v + (size_t)NROWS * DQK;

    qkv_proj_kernel<<<dim3(24, 8, 3), 256, 0, stream>>>(feat, Wq, Wk, Wv, q, k, v);
    norm_rope_kernel<<<dim3(384), 256, 0, stream>>>(q, k, coords, seq, qw, kw, pf);
    attn_kernel<<<dim3(96, 2), 256, 0, stream>>>(q, k, v, ao);
    oproj_kernel<<<dim3(12, 16), 256, 0, stream>>>(ao, Wo, (float*)d_out);
}

// Round 3
// 366.766 us; speedup vs baseline: 2.5026x; 1.6149x over previous
//
#include <hip/hip_runtime.h>
#include <math.h>

// Problem constants
#define NG   12
#define NH   8
#define CIN  64
#define CQK  32
#define CVAL 32
#define COUT 64
#define NB   2
#define NN   512
#define NROWS (NB * NN)     // 1024
#define GHH  (NG * NH)      // 96 heads
#define DIN  (NG * CIN)     // 768
#define DQK  (GHH * CQK)    // 3072
#define DOUT (NG * COUT)    // 768

typedef __attribute__((ext_vector_type(8))) short bf16x8;
typedef __attribute__((ext_vector_type(4))) float f32x4;
typedef unsigned short ushort_t;

// ---------------------------------------------------------------------------
// split fp32 -> (hi, lo) bf16 planes.  x = hi + lo + O(2^-16 x).
// ---------------------------------------------------------------------------
__device__ __forceinline__ ushort_t bf16_rne(float v) {
    unsigned u = __float_as_uint(v);
    return (ushort_t)((u + 0x7fffu + ((u >> 16) & 1u)) >> 16);
}

__global__ __launch_bounds__(256) void split_kernel(
    const float* __restrict__ in, ushort_t* __restrict__ hi,
    ushort_t* __restrict__ lo, int n4)
{
    int i = blockIdx.x * 256 + threadIdx.x;
    if (i >= n4) return;
    float4 x = ((const float4*)in)[i];
    ushort_t h[4], l[4];
    float vv[4] = {x.x, x.y, x.z, x.w};
    #pragma unroll
    for (int c = 0; c < 4; ++c) {
        ushort_t hb = bf16_rne(vv[c]);
        float hf = __uint_as_float(((unsigned)hb) << 16);
        h[c] = hb;
        l[c] = bf16_rne(vv[c] - hf);
    }
    ((ushort4*)hi)[i] = make_ushort4(h[0], h[1], h[2], h[3]);
    ((ushort4*)lo)[i] = make_ushort4(l[0], l[1], l[2], l[3]);
}

// ---------------------------------------------------------------------------
// Kernel 1: block-circulant QKV projection, split-bf16 MFMA.
// out[m, hg*256+o] = sum_g sum_i x[m][g*64+i] * W[(g-hg)%12][o][i]
// 128x128 block tile, 4 waves, wave-tile 64x64 (4x4 MFMA positions).
// 3 MFMAs per position per k-step: Ah*Bh + Ah*Bl + Al*Bh.
// LDS K-stride padded 32->40 bf16: fragment ds_read_b128 lands 8 reqs/bank.
// ---------------------------------------------------------------------------
__global__ __launch_bounds__(256, 1) void qkv_mfma_kernel(
    const ushort_t* __restrict__ Xhi, const ushort_t* __restrict__ Xlo,
    const ushort_t* __restrict__ Whi, const ushort_t* __restrict__ Wlo, // [z][12][256][64]
    float* __restrict__ qo, float* __restrict__ ko, float* __restrict__ vo)
{
    __shared__ __attribute__((aligned(16))) ushort_t As[2][128][40];
    __shared__ __attribute__((aligned(16))) ushort_t Bs[2][128][40];
    const int z = blockIdx.z;
    float* __restrict__ out = (z == 0) ? qo : (z == 1) ? ko : vo;
    const ushort_t* Wh = Whi + (size_t)z * NG * 256 * 64;
    const ushort_t* Wl = Wlo + (size_t)z * NG * 256 * 64;
    const int m0 = blockIdx.y * 128;
    const int c0 = blockIdx.x * 128;
    const int hg = c0 >> 8;
    const int o0 = c0 & 255;
    const int tid  = threadIdx.x;
    const int srow = tid & 127;
    const int spl  = tid >> 7;       // staging plane 0=hi 1=lo
    const int lane = tid & 63;
    const int w    = tid >> 6;
    const int wm   = (w >> 1) * 64;
    const int wn   = (w & 1) * 64;
    const int lm   = lane & 15;
    const int lq   = lane >> 4;

    f32x4 acc[4][4];
    #pragma unroll
    for (int i = 0; i < 4; ++i)
        #pragma unroll
        for (int j = 0; j < 4; ++j) acc[i][j] = (f32x4)(0.0f);

    const ushort_t* Xp = (spl ? Xlo : Xhi) + (size_t)(m0 + srow) * DIN;
    const ushort_t* Wp = (spl ? Wl : Wh);

    for (int ks = 0; ks < 24; ++ks) {
        const int g  = ks >> 1;
        const int i0 = (ks & 1) * 32;
        int gp = g - hg; if (gp < 0) gp += NG;
        const uint4* pa = (const uint4*)(Xp + ks * 32);
        const uint4* pb = (const uint4*)(Wp + ((size_t)gp * 256 + o0 + srow) * 64 + i0);
        uint4 a0 = pa[0], a1 = pa[1], a2 = pa[2], a3 = pa[3];
        uint4 b0 = pb[0], b1 = pb[1], b2 = pb[2], b3 = pb[3];
        __syncthreads();
        *(uint4*)&As[spl][srow][0]  = a0;
        *(uint4*)&As[spl][srow][8]  = a1;
        *(uint4*)&As[spl][srow][16] = a2;
        *(uint4*)&As[spl][srow][24] = a3;
        *(uint4*)&Bs[spl][srow][0]  = b0;
        *(uint4*)&Bs[spl][srow][8]  = b1;
        *(uint4*)&Bs[spl][srow][16] = b2;
        *(uint4*)&Bs[spl][srow][24] = b3;
        __syncthreads();

        bf16x8 ah[4], al[4], bh[4], bl[4];
        #pragma unroll
        for (int t = 0; t < 4; ++t) {
            ah[t] = *(const bf16x8*)&As[0][wm + t * 16 + lm][lq * 8];
            al[t] = *(const bf16x8*)&As[1][wm + t * 16 + lm][lq * 8];
            bh[t] = *(const bf16x8*)&Bs[0][wn + t * 16 + lm][lq * 8];
            bl[t] = *(const bf16x8*)&Bs[1][wn + t * 16 + lm][lq * 8];
        }
        #pragma unroll
        for (int mt = 0; mt < 4; ++mt)
            #pragma unroll
            for (int nt = 0; nt < 4; ++nt) {
                acc[mt][nt] = __builtin_amdgcn_mfma_f32_16x16x32_bf16(ah[mt], bh[nt], acc[mt][nt], 0, 0, 0);
                acc[mt][nt] = __builtin_amdgcn_mfma_f32_16x16x32_bf16(ah[mt], bl[nt], acc[mt][nt], 0, 0, 0);
                acc[mt][nt] = __builtin_amdgcn_mfma_f32_16x16x32_bf16(al[mt], bh[nt], acc[mt][nt], 0, 0, 0);
            }
    }
    #pragma unroll
    for (int mt = 0; mt < 4; ++mt)
        #pragma unroll
        for (int r = 0; r < 4; ++r) {
            float* dst = out + (size_t)(m0 + wm + mt * 16 + lq * 4 + r) * DQK + c0 + wn + lm;
            #pragma unroll
            for (int nt = 0; nt < 4; ++nt) dst[nt * 16] = acc[mt][nt][r];
        }
}

// ---------------------------------------------------------------------------
// Kernel 2: RMSNorm + fused sequence-rope + platonic-rope (unchanged).
// ---------------------------------------------------------------------------
__global__ __launch_bounds__(256) void norm_rope_kernel(
    float* __restrict__ q, float* __restrict__ k,
    const float* __restrict__ coords,
    const int* __restrict__ seq,
    const float* __restrict__ qw,
    const float* __restrict__ kw,
    const float* __restrict__ pf)
{
    const int hid = blockIdx.x * 256 + threadIdx.x;
    const int gh = hid % GHH;
    const int bn = hid / GHH;
    const int g = gh >> 3;
    const int h = gh & 7;
    float* qp = q + (size_t)hid * CQK;
    float* kp = k + (size_t)hid * CQK;
    float xq[CQK], xk[CQK];
    #pragma unroll
    for (int u = 0; u < 8; ++u) *(float4*)(xq + 4 * u) = *(const float4*)(qp + 4 * u);
    #pragma unroll
    for (int u = 0; u < 8; ++u) *(float4*)(xk + 4 * u) = *(const float4*)(kp + 4 * u);

    float sq = 0.f, sk = 0.f;
    #pragma unroll
    for (int c = 0; c < CQK; ++c) { sq = fmaf(xq[c], xq[c], sq); sk = fmaf(xk[c], xk[c], sk); }
    const float eps = 1.1920928955078125e-07f;
    const float invq = rsqrtf(sq * (1.f / CQK) + eps);
    const float invk = rsqrtf(sk * (1.f / CQK) + eps);
    #pragma unroll
    for (int c = 0; c < CQK; ++c) { xq[c] *= invq * qw[c]; xk[c] *= invk * kw[c]; }

    const float pos = (float)seq[bn];
    const float cx = coords[bn * 3 + 0], cy = coords[bn * 3 + 1], cz = coords[bn * 3 + 2];
    float sg, cg;
    sincosf((float)g * 0.5235987755982988f, &sg, &cg);
    const float u0 = cg * cx + sg * cy;
    const float u1 = cg * cy - sg * cx;
    const float u2 = cz;

    #pragma unroll
    for (int f = 0; f < 16; ++f) {
        const float invf = exp2f(-(float)f * 0.8304820237218405f);
        const float* fr = pf + ((size_t)h * 16 + f) * 3;
        const float ang = fmaf(pos, invf, u0 * fr[0] + u1 * fr[1] + u2 * fr[2]);
        float sn, cs;
        sincosf(ang, &sn, &cs);
        float a1 = xq[2 * f], a2 = xq[2 * f + 1];
        xq[2 * f]     = a1 * cs - a2 * sn;
        xq[2 * f + 1] = a1 * sn + a2 * cs;
        float b1 = xk[2 * f], b2 = xk[2 * f + 1];
        xk[2 * f]     = b1 * cs - b2 * sn;
        xk[2 * f + 1] = b1 * sn + b2 * cs;
    }
    #pragma unroll
    for (int u = 0; u < 8; ++u) *(float4*)(qp + 4 * u) = *(const float4*)(xq + 4 * u);
    #pragma unroll
    for (int u = 0; u < 8; ++u) *(float4*)(kp + 4 * u) = *(const float4*)(xk + 4 * u);
}

// ---------------------------------------------------------------------------
// Kernel 3: attention, LDS-staged K/V (unchanged from round 2).
// ---------------------------------------------------------------------------
__global__ __launch_bounds__(256, 1) void attn_kernel(
    const float* __restrict__ q,
    const float* __restrict__ k,
    const float* __restrict__ v,
    float* __restrict__ out)
{
    __shared__ float Ks[128][CQK];
    __shared__ float Vs[128][CVAL];
    const int gh = blockIdx.x;
    const int b  = blockIdx.y;
    const size_t headoff = (size_t)b * NN * DQK + (size_t)gh * CQK;
    const int tid = threadIdx.x;
    const int r0 = tid;
    const int r1 = tid + 256;

    const float scale = 0.17677669529663687f;
    float qr[2][CQK];
    {
        const float* qp0 = q + headoff + (size_t)r0 * DQK;
        const float* qp1 = q + headoff + (size_t)r1 * DQK;
        #pragma unroll
        for (int u = 0; u < 8; ++u) {
            float4 t0 = *(const float4*)(qp0 + 4 * u);
            float4 t1 = *(const float4*)(qp1 + 4 * u);
            qr[0][4*u] = t0.x * scale; qr[0][4*u+1] = t0.y * scale;
            qr[0][4*u+2] = t0.z * scale; qr[0][4*u+3] = t0.w * scale;
            qr[1][4*u] = t1.x * scale; qr[1][4*u+1] = t1.y * scale;
            qr[1][4*u+2] = t1.z * scale; qr[1][4*u+3] = t1.w * scale;
        }
    }

    float m0v = -3.0e38f, m1v = -3.0e38f, l0 = 0.f, l1 = 0.f;
    float acc[2][CVAL];
    #pragma unroll
    for (int c = 0; c < CVAL; ++c) { acc[0][c] = 0.f; acc[1][c] = 0.f; }

    const int lr = tid >> 1;
    const int lc = (tid & 1) * 16;

    for (int j0 = 0; j0 < NN; j0 += 128) {
        const float* kp = k + headoff + (size_t)(j0 + lr) * DQK + lc;
        const float* vp = v + headoff + (size_t)(j0 + lr) * DQK + lc;
        #pragma unroll
        for (int u = 0; u < 4; ++u)
            *(float4*)&Ks[lr][lc + 4 * u] = *(const float4*)(kp + 4 * u);
        #pragma unroll
        for (int u = 0; u < 4; ++u)
            *(float4*)&Vs[lr][lc + 4 * u] = *(const float4*)(vp + 4 * u);
        __syncthreads();

        for (int jc = 0; jc < 128; jc += 16) {
            float s[2][16];
            #pragma unroll
            for (int jj = 0; jj < 16; ++jj) {
                float a0 = 0.f, a1 = 0.f, b0 = 0.f, b1 = 0.f;
                #pragma unroll
                for (int c = 0; c < CQK; c += 4) {
                    float4 kv = *(const float4*)&Ks[jc + jj][c];
                    a0 = fmaf(qr[0][c + 0], kv.x, a0);
                    a1 = fmaf(qr[0][c + 1], kv.y, a1);
                    a0 = fmaf(qr[0][c + 2], kv.z, a0);
                    a1 = fmaf(qr[0][c + 3], kv.w, a1);
                    b0 = fmaf(qr[1][c + 0], kv.x, b0);
                    b1 = fmaf(qr[1][c + 1], kv.y, b1);
                    b0 = fmaf(qr[1][c + 2], kv.z, b0);
                    b1 = fmaf(qr[1][c + 3], kv.w, b1);
                }
                s[0][jj] = a0 + a1;
                s[1][jj] = b0 + b1;
            }
            float tm0 = s[0][0], tm1 = s[1][0];
            #pragma unroll
            for (int jj = 1; jj < 16; ++jj) {
                tm0 = fmaxf(tm0, s[0][jj]);
                tm1 = fmaxf(tm1, s[1][jj]);
            }
            const float mn0 = fmaxf(m0v, tm0);
            const float mn1 = fmaxf(m1v, tm1);
            const float cr0 = __expf(m0v - mn0);
            const float cr1 = __expf(m1v - mn1);
            l0 *= cr0; l1 *= cr1;
            #pragma unroll
            for (int c = 0; c < CVAL; ++c) { acc[0][c] *= cr0; acc[1][c] *= cr1; }
            #pragma unroll
            for (int jj = 0; jj < 16; ++jj) {
                const float p0 = __expf(s[0][jj] - mn0);
                const float p1 = __expf(s[1][jj] - mn1);
                l0 += p0; l1 += p1;
                #pragma unroll
                for (int c = 0; c < CVAL; c += 4) {
                    float4 vv = *(const float4*)&Vs[jc + jj][c];
                    acc[0][c + 0] = fmaf(p0, vv.x, acc[0][c + 0]);
                    acc[0][c + 1] = fmaf(p0, vv.y, acc[0][c + 1]);
                    acc[0][c + 2] = fmaf(p0, vv.z, acc[0][c + 2]);
                    acc[0][c + 3] = fmaf(p0, vv.w, acc[0][c + 3]);
                    acc[1][c + 0] = fmaf(p1, vv.x, acc[1][c + 0]);
                    acc[1][c + 1] = fmaf(p1, vv.y, acc[1][c + 1]);
                    acc[1][c + 2] = fmaf(p1, vv.z, acc[1][c + 2]);
                    acc[1][c + 3] = fmaf(p1, vv.w, acc[1][c + 3]);
                }
            }
            m0v = mn0; m1v = mn1;
        }
        __syncthreads();
    }

    const float inv0 = 1.f / l0;
    const float inv1 = 1.f / l1;
    float* op0 = out + headoff + (size_t)r0 * DQK;
    float* op1 = out + headoff + (size_t)r1 * DQK;
    #pragma unroll
    for (int u = 0; u < 8; ++u) {
        *(float4*)(op0 + 4 * u) = make_float4(acc[0][4*u] * inv0, acc[0][4*u+1] * inv0,
                                              acc[0][4*u+2] * inv0, acc[0][4*u+3] * inv0);
        *(float4*)(op1 + 4 * u) = make_float4(acc[1][4*u] * inv1, acc[1][4*u+1] * inv1,
                                              acc[1][4*u+2] * inv1, acc[1][4*u+3] * inv1);
    }
}

// ---------------------------------------------------------------------------
// Kernel 4: output projection, split-bf16 MFMA with split-K=4.
// out[m, h*64+o] = sum_g sum_i ao[m][g*256+i] * Wo[(g-h)%12][o][i]
// Block tile 128m x 64n, 4 waves (wave-tile 64x32), K-range 768 per kz.
// ---------------------------------------------------------------------------
__global__ __launch_bounds__(256, 1) void oproj_mfma_kernel(
    const ushort_t* __restrict__ Ahi, const ushort_t* __restrict__ Alo,   // [1024][3072]
    const ushort_t* __restrict__ Wohi, const ushort_t* __restrict__ Wolo, // [12][64][256]
    float* __restrict__ part)                                             // [4][1024][768]
{
    __shared__ __attribute__((aligned(16))) ushort_t As[2][128][40];
    __shared__ __attribute__((aligned(16))) ushort_t Bs[2][64][40];
    const int h  = blockIdx.x;
    const int m0 = blockIdx.y * 128;
    const int kz = blockIdx.z;
    const int tid  = threadIdx.x;
    const int srow = tid & 127;
    const int spl  = tid >> 7;
    const int lane = tid & 63;
    const int w    = tid >> 6;
    const int wm   = (w >> 1) * 64;
    const int wn   = (w & 1) * 32;
    const int lm   = lane & 15;
    const int lq   = lane >> 4;

    f32x4 acc[4][2];
    #pragma unroll
    for (int i = 0; i < 4; ++i) { acc[i][0] = (f32x4)(0.0f); acc[i][1] = (f32x4)(0.0f); }

    const ushort_t* Ap = (spl ? Alo : Ahi) + (size_t)(m0 + srow) * DQK;
    const int brow = tid & 63;
    const int bpl  = (tid >> 6) & 1;
    const ushort_t* Wp = (bpl ? Wolo : Wohi);

    for (int ks = 0; ks < 24; ++ks) {
        const int kk = kz * 768 + ks * 32;
        const int g  = kk >> 8;
        const int il = kk & 255;
        int gp = g - h; if (gp < 0) gp += NG;
        const uint4* pa = (const uint4*)(Ap + kk);
        uint4 a0 = pa[0], a1 = pa[1], a2 = pa[2], a3 = pa[3];
        uint4 b0, b1, b2, b3;
        if (tid < 128) {
            const uint4* pb = (const uint4*)(Wp + ((size_t)gp * 64 + brow) * 256 + il);
            b0 = pb[0]; b1 = pb[1]; b2 = pb[2]; b3 = pb[3];
        }
        __syncthreads();
        *(uint4*)&As[spl][srow][0]  = a0;
        *(uint4*)&As[spl][srow][8]  = a1;
        *(uint4*)&As[spl][srow][16] = a2;
        *(uint4*)&As[spl][srow][24] = a3;
        if (tid < 128) {
            *(uint4*)&Bs[bpl][brow][0]  = b0;
            *(uint4*)&Bs[bpl][brow][8]  = b1;
            *(uint4*)&Bs[bpl][brow][16] = b2;
            *(uint4*)&Bs[bpl][brow][24] = b3;
        }
        __syncthreads();

        bf16x8 ah[4], al[4], bh[2], bl[2];
        #pragma unroll
        for (int t = 0; t < 4; ++t) {
            ah[t] = *(const bf16x8*)&As[0][wm + t * 16 + lm][lq * 8];
            al[t] = *(const bf16x8*)&As[1][wm + t * 16 + lm][lq * 8];
        }
        #pragma unroll
        for (int t = 0; t < 2; ++t) {
            bh[t] = *(const bf16x8*)&Bs[0][wn + t * 16 + lm][lq * 8];
            bl[t] = *(const bf16x8*)&Bs[1][wn + t * 16 + lm][lq * 8];
        }
        #pragma unroll
        for (int mt = 0; mt < 4; ++mt)
            #pragma unroll
            for (int nt = 0; nt < 2; ++nt) {
                acc[mt][nt] = __builtin_amdgcn_mfma_f32_16x16x32_bf16(ah[mt], bh[nt], acc[mt][nt], 0, 0, 0);
                acc[mt][nt] = __builtin_amdgcn_mfma_f32_16x16x32_bf16(ah[mt], bl[nt], acc[mt][nt], 0, 0, 0);
                acc[mt][nt] = __builtin_amdgcn_mfma_f32_16x16x32_bf16(al[mt], bh[nt], acc[mt][nt], 0, 0, 0);
            }
    }
    float* dst0 = part + (size_t)kz * (NROWS * DOUT);
    #pragma unroll
    for (int mt = 0; mt < 4; ++mt)
        #pragma unroll
        for (int r = 0; r < 4; ++r) {
            float* dst = dst0 + (size_t)(m0 + wm + mt * 16 + lq * 4 + r) * DOUT + h * 64 + wn + lm;
            dst[0]  = acc[mt][0][r];
            dst[16] = acc[mt][1][r];
        }
}

__global__ __launch_bounds__(256) void reduce4_kernel(
    const float* __restrict__ part, float* __restrict__ out)
{
    const int i = blockIdx.x * 256 + threadIdx.x;   // over 196608 float4s
    const float4* p = (const float4*)part;
    const int s = NROWS * DOUT / 4;                 // 196608
    float4 a = p[i], b = p[i + s], c = p[i + 2 * s], d = p[i + 3 * s];
    ((float4*)out)[i] = make_float4(a.x + b.x + c.x + d.x, a.y + b.y + c.y + d.y,
                                    a.z + b.z + c.z + d.z, a.w + b.w + c.w + d.w);
}

// ---------------------------------------------------------------------------
extern "C" void kernel_launch(void* const* d_in, const int* in_sizes, int n_in,
                              void* d_out, int out_size, void* d_ws, size_t ws_size,
                              hipStream_t stream)
{
    const float* feat   = (const float*)d_in[0];
    const float* coords = (const float*)d_in[1];
    const float* Wq     = (const float*)d_in[2];
    const float* Wk     = (const float*)d_in[3];
    const float* Wv     = (const float*)d_in[4];
    const float* Wo     = (const float*)d_in[5];
    const float* qw     = (const float*)d_in[6];
    const float* kw     = (const float*)d_in[7];
    const float* pf     = (const float*)d_in[8];
    const int*   seq    = (const int*)d_in[9];

    const size_t SZ = (size_t)NROWS * DQK;          // 3145728 floats
    float* q  = (float*)d_ws;
    float* k  = q + SZ;
    float* v  = k + SZ;
    float* ao = v + SZ;

    // bf16 hi/lo planes for x + Wqkv live in the (currently dead) ao region
    ushort_t* Xhi  = (ushort_t*)ao;
    ushort_t* Xlo  = Xhi + (size_t)NROWS * DIN;              // 786432
    ushort_t* Wqh  = Xlo + (size_t)NROWS * DIN;
    ushort_t* Wql  = Wqh + (size_t)3 * NG * 256 * 64;        // 589824
    // after attention: ao splits into q region, Wo splits into v region,
    // oproj partials into k region (all dead by then)
    ushort_t* AOhi = (ushort_t*)q;
    ushort_t* AOlo = AOhi + SZ;
    ushort_t* WOhi = (ushort_t*)v;
    ushort_t* WOlo = WOhi + (size_t)NG * COUT * 256;         // 196608
    float*    part = k;                                      // 4 x 786432 floats

    const int NW = NG * 256 * 64;                            // 196608 per matrix

    split_kernel<<<dim3(768),  256, 0, stream>>>(feat, Xhi, Xlo, (NROWS * DIN) / 4);
    split_kernel<<<dim3(192),  256, 0, stream>>>(Wq, Wqh,          Wql,          NW / 4);
    split_kernel<<<dim3(192),  256, 0, stream>>>(Wk, Wqh + NW,     Wql + NW,     NW / 4);
    split_kernel<<<dim3(192),  256, 0, stream>>>(Wv, Wqh + 2 * NW, Wql + 2 * NW, NW / 4);

    qkv_mfma_kernel<<<dim3(24, 8, 3), 256, 0, stream>>>(Xhi, Xlo, Wqh, Wql, q, k, v);
    norm_rope_kernel<<<dim3(384), 256, 0, stream>>>(q, k, coords, seq, qw, kw, pf);
    attn_kernel<<<dim3(96, 2), 256, 0, stream>>>(q, k, v, ao);

    split_kernel<<<dim3(192),  256, 0, stream>>>(Wo, WOhi, WOlo, (NG * COUT * 256) / 4);
    split_kernel<<<dim3(3072), 256, 0, stream>>>(ao, AOhi, AOlo, (int)(SZ / 4));
    oproj_mfma_kernel<<<dim3(12, 8, 4), 256, 0, stream>>>(AOhi, AOlo, WOhi, WOlo, part);
    reduce4_kernel<<<dim3(768), 256, 0, stream>>>(part, (float*)d_out);
}

// Round 4
// 348.877 us; speedup vs baseline: 2.6309x; 1.0513x over previous
//
#include <hip/hip_runtime.h>
#include <math.h>

// Problem constants
#define NG   12
#define NH   8
#define CIN  64
#define CQK  32
#define CVAL 32
#define COUT 64
#define NB   2
#define NN   512
#define NROWS (NB * NN)     // 1024
#define GHH  (NG * NH)      // 96 heads
#define DIN  (NG * CIN)     // 768
#define DQK  (GHH * CQK)    // 3072
#define DOUT (NG * COUT)    // 768

typedef __attribute__((ext_vector_type(8))) short bf16x8;
typedef __attribute__((ext_vector_type(4))) float f32x4;
typedef unsigned short ushort_t;

// ---------------------------------------------------------------------------
// split fp32 -> (hi, lo) bf16 planes.  x = hi + lo + O(2^-16 x).
// ---------------------------------------------------------------------------
__device__ __forceinline__ ushort_t bf16_rne(float v) {
    unsigned u = __float_as_uint(v);
    return (ushort_t)((u + 0x7fffu + ((u >> 16) & 1u)) >> 16);
}

__global__ __launch_bounds__(256) void split_kernel(
    const float* __restrict__ in, ushort_t* __restrict__ hi,
    ushort_t* __restrict__ lo, int n4)
{
    int i = blockIdx.x * 256 + threadIdx.x;
    if (i >= n4) return;
    float4 x = ((const float4*)in)[i];
    ushort_t h[4], l[4];
    float vv[4] = {x.x, x.y, x.z, x.w};
    #pragma unroll
    for (int c = 0; c < 4; ++c) {
        ushort_t hb = bf16_rne(vv[c]);
        float hf = __uint_as_float(((unsigned)hb) << 16);
        h[c] = hb;
        l[c] = bf16_rne(vv[c] - hf);
    }
    ((ushort4*)hi)[i] = make_ushort4(h[0], h[1], h[2], h[3]);
    ((ushort4*)lo)[i] = make_ushort4(l[0], l[1], l[2], l[3]);
}

// ---------------------------------------------------------------------------
// Kernel 1: block-circulant QKV projection, split-bf16 MFMA (unchanged).
// ---------------------------------------------------------------------------
__global__ __launch_bounds__(256, 1) void qkv_mfma_kernel(
    const ushort_t* __restrict__ Xhi, const ushort_t* __restrict__ Xlo,
    const ushort_t* __restrict__ Whi, const ushort_t* __restrict__ Wlo, // [z][12][256][64]
    float* __restrict__ qo, float* __restrict__ ko, float* __restrict__ vo)
{
    __shared__ __attribute__((aligned(16))) ushort_t As[2][128][40];
    __shared__ __attribute__((aligned(16))) ushort_t Bs[2][128][40];
    const int z = blockIdx.z;
    float* __restrict__ out = (z == 0) ? qo : (z == 1) ? ko : vo;
    const ushort_t* Wh = Whi + (size_t)z * NG * 256 * 64;
    const ushort_t* Wl = Wlo + (size_t)z * NG * 256 * 64;
    const int m0 = blockIdx.y * 128;
    const int c0 = blockIdx.x * 128;
    const int hg = c0 >> 8;
    const int o0 = c0 & 255;
    const int tid  = threadIdx.x;
    const int srow = tid & 127;
    const int spl  = tid >> 7;       // staging plane 0=hi 1=lo
    const int lane = tid & 63;
    const int w    = tid >> 6;
    const int wm   = (w >> 1) * 64;
    const int wn   = (w & 1) * 64;
    const int lm   = lane & 15;
    const int lq   = lane >> 4;

    f32x4 acc[4][4];
    #pragma unroll
    for (int i = 0; i < 4; ++i)
        #pragma unroll
        for (int j = 0; j < 4; ++j) acc[i][j] = (f32x4)(0.0f);

    const ushort_t* Xp = (spl ? Xlo : Xhi) + (size_t)(m0 + srow) * DIN;
    const ushort_t* Wp = (spl ? Wl : Wh);

    for (int ks = 0; ks < 24; ++ks) {
        const int g  = ks >> 1;
        const int i0 = (ks & 1) * 32;
        int gp = g - hg; if (gp < 0) gp += NG;
        const uint4* pa = (const uint4*)(Xp + ks * 32);
        const uint4* pb = (const uint4*)(Wp + ((size_t)gp * 256 + o0 + srow) * 64 + i0);
        uint4 a0 = pa[0], a1 = pa[1], a2 = pa[2], a3 = pa[3];
        uint4 b0 = pb[0], b1 = pb[1], b2 = pb[2], b3 = pb[3];
        __syncthreads();
        *(uint4*)&As[spl][srow][0]  = a0;
        *(uint4*)&As[spl][srow][8]  = a1;
        *(uint4*)&As[spl][srow][16] = a2;
        *(uint4*)&As[spl][srow][24] = a3;
        *(uint4*)&Bs[spl][srow][0]  = b0;
        *(uint4*)&Bs[spl][srow][8]  = b1;
        *(uint4*)&Bs[spl][srow][16] = b2;
        *(uint4*)&Bs[spl][srow][24] = b3;
        __syncthreads();

        bf16x8 ah[4], al[4], bh[4], bl[4];
        #pragma unroll
        for (int t = 0; t < 4; ++t) {
            ah[t] = *(const bf16x8*)&As[0][wm + t * 16 + lm][lq * 8];
            al[t] = *(const bf16x8*)&As[1][wm + t * 16 + lm][lq * 8];
            bh[t] = *(const bf16x8*)&Bs[0][wn + t * 16 + lm][lq * 8];
            bl[t] = *(const bf16x8*)&Bs[1][wn + t * 16 + lm][lq * 8];
        }
        #pragma unroll
        for (int mt = 0; mt < 4; ++mt)
            #pragma unroll
            for (int nt = 0; nt < 4; ++nt) {
                acc[mt][nt] = __builtin_amdgcn_mfma_f32_16x16x32_bf16(ah[mt], bh[nt], acc[mt][nt], 0, 0, 0);
                acc[mt][nt] = __builtin_amdgcn_mfma_f32_16x16x32_bf16(ah[mt], bl[nt], acc[mt][nt], 0, 0, 0);
                acc[mt][nt] = __builtin_amdgcn_mfma_f32_16x16x32_bf16(al[mt], bh[nt], acc[mt][nt], 0, 0, 0);
            }
    }
    #pragma unroll
    for (int mt = 0; mt < 4; ++mt)
        #pragma unroll
        for (int r = 0; r < 4; ++r) {
            float* dst = out + (size_t)(m0 + wm + mt * 16 + lq * 4 + r) * DQK + c0 + wn + lm;
            #pragma unroll
            for (int nt = 0; nt < 4; ++nt) dst[nt * 16] = acc[mt][nt][r];
        }
}

// ---------------------------------------------------------------------------
// Kernel 2: RMSNorm + fused sequence-rope + platonic-rope (unchanged).
// ---------------------------------------------------------------------------
__global__ __launch_bounds__(256) void norm_rope_kernel(
    float* __restrict__ q, float* __restrict__ k,
    const float* __restrict__ coords,
    const int* __restrict__ seq,
    const float* __restrict__ qw,
    const float* __restrict__ kw,
    const float* __restrict__ pf)
{
    const int hid = blockIdx.x * 256 + threadIdx.x;
    const int gh = hid % GHH;
    const int bn = hid / GHH;
    const int g = gh >> 3;
    const int h = gh & 7;
    float* qp = q + (size_t)hid * CQK;
    float* kp = k + (size_t)hid * CQK;
    float xq[CQK], xk[CQK];
    #pragma unroll
    for (int u = 0; u < 8; ++u) *(float4*)(xq + 4 * u) = *(const float4*)(qp + 4 * u);
    #pragma unroll
    for (int u = 0; u < 8; ++u) *(float4*)(xk + 4 * u) = *(const float4*)(kp + 4 * u);

    float sq = 0.f, sk = 0.f;
    #pragma unroll
    for (int c = 0; c < CQK; ++c) { sq = fmaf(xq[c], xq[c], sq); sk = fmaf(xk[c], xk[c], sk); }
    const float eps = 1.1920928955078125e-07f;
    const float invq = rsqrtf(sq * (1.f / CQK) + eps);
    const float invk = rsqrtf(sk * (1.f / CQK) + eps);
    #pragma unroll
    for (int c = 0; c < CQK; ++c) { xq[c] *= invq * qw[c]; xk[c] *= invk * kw[c]; }

    const float pos = (float)seq[bn];
    const float cx = coords[bn * 3 + 0], cy = coords[bn * 3 + 1], cz = coords[bn * 3 + 2];
    float sg, cg;
    sincosf((float)g * 0.5235987755982988f, &sg, &cg);
    const float u0 = cg * cx + sg * cy;
    const float u1 = cg * cy - sg * cx;
    const float u2 = cz;

    #pragma unroll
    for (int f = 0; f < 16; ++f) {
        const float invf = exp2f(-(float)f * 0.8304820237218405f);
        const float* fr = pf + ((size_t)h * 16 + f) * 3;
        const float ang = fmaf(pos, invf, u0 * fr[0] + u1 * fr[1] + u2 * fr[2]);
        float sn, cs;
        sincosf(ang, &sn, &cs);
        float a1 = xq[2 * f], a2 = xq[2 * f + 1];
        xq[2 * f]     = a1 * cs - a2 * sn;
        xq[2 * f + 1] = a1 * sn + a2 * cs;
        float b1 = xk[2 * f], b2 = xk[2 * f + 1];
        xk[2 * f]     = b1 * cs - b2 * sn;
        xk[2 * f + 1] = b1 * sn + b2 * cs;
    }
    #pragma unroll
    for (int u = 0; u < 8; ++u) *(float4*)(qp + 4 * u) = *(const float4*)(xq + 4 * u);
    #pragma unroll
    for (int u = 0; u < 8; ++u) *(float4*)(kp + 4 * u) = *(const float4*)(xk + 4 * u);
}

// ---------------------------------------------------------------------------
// Kernel 3 (REWRITTEN): attention, c-split lane pairs for 4x wave parallelism.
// Block = 256 threads = 128 q-rows (lane pair 2r/2r+1 owns the two 16-dim
// halves of row r). Partial QK dot exchanged via __shfl_xor(d,1); softmax
// state duplicated in the pair; PV + output naturally c-partitioned.
// Grid = (96 heads, 4 row-chunks, 2 batch) = 768 blocks = 3 waves/SIMD.
// ---------------------------------------------------------------------------
__global__ __launch_bounds__(256, 1) void attn_kernel(
    const float* __restrict__ q,
    const float* __restrict__ k,
    const float* __restrict__ v,
    float* __restrict__ out)
{
    __shared__ float Ks[128][CQK];
    __shared__ float Vs[128][CVAL];
    const int gh    = blockIdx.x;
    const int chunk = blockIdx.y;
    const int b     = blockIdx.z;
    const size_t headoff = (size_t)b * NN * DQK + (size_t)gh * CQK;
    const int tid = threadIdx.x;
    const int pr  = tid >> 1;            // 0..127: row within chunk
    const int ch  = (tid & 1) * 16;      // c-half offset
    const int row = chunk * 128 + pr;

    const float scale = 0.17677669529663687f;  // 1/sqrt(32)
    float qr[16];
    {
        const float* qp = q + headoff + (size_t)row * DQK + ch;
        #pragma unroll
        for (int u = 0; u < 4; ++u) {
            float4 t = *(const float4*)(qp + 4 * u);
            qr[4*u]   = t.x * scale; qr[4*u+1] = t.y * scale;
            qr[4*u+2] = t.z * scale; qr[4*u+3] = t.w * scale;
        }
    }

    float mv = -3.0e38f, l = 0.f;
    float acc[16];
    #pragma unroll
    for (int c = 0; c < 16; ++c) acc[c] = 0.f;

    for (int j0 = 0; j0 < NN; j0 += 128) {
        // ---- stage K/V tile (pr/ch double as staging row/col-half) ----
        const float* kp = k + headoff + (size_t)(j0 + pr) * DQK + ch;
        const float* vp = v + headoff + (size_t)(j0 + pr) * DQK + ch;
        #pragma unroll
        for (int u = 0; u < 4; ++u)
            *(float4*)&Ks[pr][ch + 4 * u] = *(const float4*)(kp + 4 * u);
        #pragma unroll
        for (int u = 0; u < 4; ++u)
            *(float4*)&Vs[pr][ch + 4 * u] = *(const float4*)(vp + 4 * u);
        __syncthreads();

        for (int jc = 0; jc < 128; jc += 16) {
            float s[16];
            #pragma unroll
            for (int jj = 0; jj < 16; ++jj) {
                float d0 = 0.f, d1 = 0.f;
                #pragma unroll
                for (int c = 0; c < 16; c += 4) {
                    float4 kv = *(const float4*)&Ks[jc + jj][ch + c];
                    d0 = fmaf(qr[c + 0], kv.x, d0);
                    d1 = fmaf(qr[c + 1], kv.y, d1);
                    d0 = fmaf(qr[c + 2], kv.z, d0);
                    d1 = fmaf(qr[c + 3], kv.w, d1);
                }
                const float d = d0 + d1;
                s[jj] = d + __shfl_xor(d, 1, 64);   // combine the two c-halves
            }
            float tm = s[0];
            #pragma unroll
            for (int jj = 1; jj < 16; ++jj) tm = fmaxf(tm, s[jj]);
            const float mn = fmaxf(mv, tm);
            const float cr = __expf(mv - mn);
            l *= cr;
            #pragma unroll
            for (int c = 0; c < 16; ++c) acc[c] *= cr;
            #pragma unroll
            for (int jj = 0; jj < 16; ++jj) {
                const float p = __expf(s[jj] - mn);
                l += p;
                #pragma unroll
                for (int c = 0; c < 16; c += 4) {
                    float4 vv = *(const float4*)&Vs[jc + jj][ch + c];
                    acc[c + 0] = fmaf(p, vv.x, acc[c + 0]);
                    acc[c + 1] = fmaf(p, vv.y, acc[c + 1]);
                    acc[c + 2] = fmaf(p, vv.z, acc[c + 2]);
                    acc[c + 3] = fmaf(p, vv.w, acc[c + 3]);
                }
            }
            mv = mn;
        }
        __syncthreads();
    }

    const float inv = 1.f / l;
    float* op = out + headoff + (size_t)row * DQK + ch;
    #pragma unroll
    for (int u = 0; u < 4; ++u)
        *(float4*)(op + 4 * u) = make_float4(acc[4*u] * inv, acc[4*u+1] * inv,
                                             acc[4*u+2] * inv, acc[4*u+3] * inv);
}

// ---------------------------------------------------------------------------
// Kernel 4: output projection, split-bf16 MFMA with split-K=4 (unchanged).
// ---------------------------------------------------------------------------
__global__ __launch_bounds__(256, 1) void oproj_mfma_kernel(
    const ushort_t* __restrict__ Ahi, const ushort_t* __restrict__ Alo,   // [1024][3072]
    const ushort_t* __restrict__ Wohi, const ushort_t* __restrict__ Wolo, // [12][64][256]
    float* __restrict__ part)                                             // [4][1024][768]
{
    __shared__ __attribute__((aligned(16))) ushort_t As[2][128][40];
    __shared__ __attribute__((aligned(16))) ushort_t Bs[2][64][40];
    const int h  = blockIdx.x;
    const int m0 = blockIdx.y * 128;
    const int kz = blockIdx.z;
    const int tid  = threadIdx.x;
    const int srow = tid & 127;
    const int spl  = tid >> 7;
    const int lane = tid & 63;
    const int w    = tid >> 6;
    const int wm   = (w >> 1) * 64;
    const int wn   = (w & 1) * 32;
    const int lm   = lane & 15;
    const int lq   = lane >> 4;

    f32x4 acc[4][2];
    #pragma unroll
    for (int i = 0; i < 4; ++i) { acc[i][0] = (f32x4)(0.0f); acc[i][1] = (f32x4)(0.0f); }

    const ushort_t* Ap = (spl ? Alo : Ahi) + (size_t)(m0 + srow) * DQK;
    const int brow = tid & 63;
    const int bpl  = (tid >> 6) & 1;
    const ushort_t* Wp = (bpl ? Wolo : Wohi);

    for (int ks = 0; ks < 24; ++ks) {
        const int kk = kz * 768 + ks * 32;
        const int g  = kk >> 8;
        const int il = kk & 255;
        int gp = g - h; if (gp < 0) gp += NG;
        const uint4* pa = (const uint4*)(Ap + kk);
        uint4 a0 = pa[0], a1 = pa[1], a2 = pa[2], a3 = pa[3];
        uint4 b0, b1, b2, b3;
        if (tid < 128) {
            const uint4* pb = (const uint4*)(Wp + ((size_t)gp * 64 + brow) * 256 + il);
            b0 = pb[0]; b1 = pb[1]; b2 = pb[2]; b3 = pb[3];
        }
        __syncthreads();
        *(uint4*)&As[spl][srow][0]  = a0;
        *(uint4*)&As[spl][srow][8]  = a1;
        *(uint4*)&As[spl][srow][16] = a2;
        *(uint4*)&As[spl][srow][24] = a3;
        if (tid < 128) {
            *(uint4*)&Bs[bpl][brow][0]  = b0;
            *(uint4*)&Bs[bpl][brow][8]  = b1;
            *(uint4*)&Bs[bpl][brow][16] = b2;
            *(uint4*)&Bs[bpl][brow][24] = b3;
        }
        __syncthreads();

        bf16x8 ah[4], al[4], bh[2], bl[2];
        #pragma unroll
        for (int t = 0; t < 4; ++t) {
            ah[t] = *(const bf16x8*)&As[0][wm + t * 16 + lm][lq * 8];
            al[t] = *(const bf16x8*)&As[1][wm + t * 16 + lm][lq * 8];
        }
        #pragma unroll
        for (int t = 0; t < 2; ++t) {
            bh[t] = *(const bf16x8*)&Bs[0][wn + t * 16 + lm][lq * 8];
            bl[t] = *(const bf16x8*)&Bs[1][wn + t * 16 + lm][lq * 8];
        }
        #pragma unroll
        for (int mt = 0; mt < 4; ++mt)
            #pragma unroll
            for (int nt = 0; nt < 2; ++nt) {
                acc[mt][nt] = __builtin_amdgcn_mfma_f32_16x16x32_bf16(ah[mt], bh[nt], acc[mt][nt], 0, 0, 0);
                acc[mt][nt] = __builtin_amdgcn_mfma_f32_16x16x32_bf16(ah[mt], bl[nt], acc[mt][nt], 0, 0, 0);
                acc[mt][nt] = __builtin_amdgcn_mfma_f32_16x16x32_bf16(al[mt], bh[nt], acc[mt][nt], 0, 0, 0);
            }
    }
    float* dst0 = part + (size_t)kz * (NROWS * DOUT);
    #pragma unroll
    for (int mt = 0; mt < 4; ++mt)
        #pragma unroll
        for (int r = 0; r < 4; ++r) {
            float* dst = dst0 + (size_t)(m0 + wm + mt * 16 + lq * 4 + r) * DOUT + h * 64 + wn + lm;
            dst[0]  = acc[mt][0][r];
            dst[16] = acc[mt][1][r];
        }
}

__global__ __launch_bounds__(256) void reduce4_kernel(
    const float* __restrict__ part, float* __restrict__ out)
{
    const int i = blockIdx.x * 256 + threadIdx.x;   // over 196608 float4s
    const float4* p = (const float4*)part;
    const int s = NROWS * DOUT / 4;                 // 196608
    float4 a = p[i], b = p[i + s], c = p[i + 2 * s], d = p[i + 3 * s];
    ((float4*)out)[i] = make_float4(a.x + b.x + c.x + d.x, a.y + b.y + c.y + d.y,
                                    a.z + b.z + c.z + d.z, a.w + b.w + c.w + d.w);
}

// ---------------------------------------------------------------------------
extern "C" void kernel_launch(void* const* d_in, const int* in_sizes, int n_in,
                              void* d_out, int out_size, void* d_ws, size_t ws_size,
                              hipStream_t stream)
{
    const float* feat   = (const float*)d_in[0];
    const float* coords = (const float*)d_in[1];
    const float* Wq     = (const float*)d_in[2];
    const float* Wk     = (const float*)d_in[3];
    const float* Wv     = (const float*)d_in[4];
    const float* Wo     = (const float*)d_in[5];
    const float* qw     = (const float*)d_in[6];
    const float* kw     = (const float*)d_in[7];
    const float* pf     = (const float*)d_in[8];
    const int*   seq    = (const int*)d_in[9];

    const size_t SZ = (size_t)NROWS * DQK;          // 3145728 floats
    float* q  = (float*)d_ws;
    float* k  = q + SZ;
    float* v  = k + SZ;
    float* ao = v + SZ;

    // bf16 hi/lo planes for x + Wqkv live in the (currently dead) ao region
    ushort_t* Xhi  = (ushort_t*)ao;
    ushort_t* Xlo  = Xhi + (size_t)NROWS * DIN;              // 786432
    ushort_t* Wqh  = Xlo + (size_t)NROWS * DIN;
    ushort_t* Wql  = Wqh + (size_t)3 * NG * 256 * 64;        // 589824
    // after attention: ao splits into q region, Wo splits into v region,
    // oproj partials into k region (all dead by then)
    ushort_t* AOhi = (ushort_t*)q;
    ushort_t* AOlo = AOhi + SZ;
    ushort_t* WOhi = (ushort_t*)v;
    ushort_t* WOlo = WOhi + (size_t)NG * COUT * 256;         // 196608
    float*    part = k;                                      // 4 x 786432 floats

    const int NW = NG * 256 * 64;                            // 196608 per matrix

    split_kernel<<<dim3(768),  256, 0, stream>>>(feat, Xhi, Xlo, (NROWS * DIN) / 4);
    split_kernel<<<dim3(192),  256, 0, stream>>>(Wq, Wqh,          Wql,          NW / 4);
    split_kernel<<<dim3(192),  256, 0, stream>>>(Wk, Wqh + NW,     Wql + NW,     NW / 4);
    split_kernel<<<dim3(192),  256, 0, stream>>>(Wv, Wqh + 2 * NW, Wql + 2 * NW, NW / 4);

    qkv_mfma_kernel<<<dim3(24, 8, 3), 256, 0, stream>>>(Xhi, Xlo, Wqh, Wql, q, k, v);
    norm_rope_kernel<<<dim3(384), 256, 0, stream>>>(q, k, coords, seq, qw, kw, pf);
    attn_kernel<<<dim3(96, 4, 2), 256, 0, stream>>>(q, k, v, ao);

    split_kernel<<<dim3(192),  256, 0, stream>>>(Wo, WOhi, WOlo, (NG * COUT * 256) / 4);
    split_kernel<<<dim3(3072), 256, 0, stream>>>(ao, AOhi, AOlo, (int)(SZ / 4));
    oproj_mfma_kernel<<<dim3(12, 8, 4), 256, 0, stream>>>(AOhi, AOlo, WOhi, WOlo, part);
    reduce4_kernel<<<dim3(768), 256, 0, stream>>>(part, (float*)d_out);
}

// Round 5
// 276.509 us; speedup vs baseline: 3.3195x; 1.2617x over previous
//
#include <hip/hip_runtime.h>
#include <math.h>

// Problem constants
#define NG   12
#define NH   8
#define CIN  64
#define CQK  32
#define CVAL 32
#define COUT 64
#define NB   2
#define NN   512
#define NROWS (NB * NN)     // 1024
#define GHH  (NG * NH)      // 96 heads
#define DIN  (NG * CIN)     // 768
#define DQK  (GHH * CQK)    // 3072
#define DOUT (NG * COUT)    // 768

typedef __attribute__((ext_vector_type(8))) short bf16x8;
typedef __attribute__((ext_vector_type(4))) float f32x4;
typedef unsigned short ushort_t;

// ---------------------------------------------------------------------------
// split fp32 -> (hi, lo) bf16 planes.  x = hi + lo + O(2^-16 x).
// ---------------------------------------------------------------------------
__device__ __forceinline__ ushort_t bf16_rne(float v) {
    unsigned u = __float_as_uint(v);
    return (ushort_t)((u + 0x7fffu + ((u >> 16) & 1u)) >> 16);
}

__global__ __launch_bounds__(256) void split_kernel(
    const float* __restrict__ in, ushort_t* __restrict__ hi,
    ushort_t* __restrict__ lo, int n4)
{
    int i = blockIdx.x * 256 + threadIdx.x;
    if (i >= n4) return;
    float4 x = ((const float4*)in)[i];
    ushort_t h[4], l[4];
    float vv[4] = {x.x, x.y, x.z, x.w};
    #pragma unroll
    for (int c = 0; c < 4; ++c) {
        ushort_t hb = bf16_rne(vv[c]);
        float hf = __uint_as_float(((unsigned)hb) << 16);
        h[c] = hb;
        l[c] = bf16_rne(vv[c] - hf);
    }
    ((ushort4*)hi)[i] = make_ushort4(h[0], h[1], h[2], h[3]);
    ((ushort4*)lo)[i] = make_ushort4(l[0], l[1], l[2], l[3]);
}

// ---------------------------------------------------------------------------
// Kernel 1: block-circulant QKV projection, split-bf16 MFMA (unchanged).
// ---------------------------------------------------------------------------
__global__ __launch_bounds__(256, 1) void qkv_mfma_kernel(
    const ushort_t* __restrict__ Xhi, const ushort_t* __restrict__ Xlo,
    const ushort_t* __restrict__ Whi, const ushort_t* __restrict__ Wlo, // [z][12][256][64]
    float* __restrict__ qo, float* __restrict__ ko, float* __restrict__ vo)
{
    __shared__ __attribute__((aligned(16))) ushort_t As[2][128][40];
    __shared__ __attribute__((aligned(16))) ushort_t Bs[2][128][40];
    const int z = blockIdx.z;
    float* __restrict__ out = (z == 0) ? qo : (z == 1) ? ko : vo;
    const ushort_t* Wh = Whi + (size_t)z * NG * 256 * 64;
    const ushort_t* Wl = Wlo + (size_t)z * NG * 256 * 64;
    const int m0 = blockIdx.y * 128;
    const int c0 = blockIdx.x * 128;
    const int hg = c0 >> 8;
    const int o0 = c0 & 255;
    const int tid  = threadIdx.x;
    const int srow = tid & 127;
    const int spl  = tid >> 7;       // staging plane 0=hi 1=lo
    const int lane = tid & 63;
    const int w    = tid >> 6;
    const int wm   = (w >> 1) * 64;
    const int wn   = (w & 1) * 64;
    const int lm   = lane & 15;
    const int lq   = lane >> 4;

    f32x4 acc[4][4];
    #pragma unroll
    for (int i = 0; i < 4; ++i)
        #pragma unroll
        for (int j = 0; j < 4; ++j) acc[i][j] = (f32x4)(0.0f);

    const ushort_t* Xp = (spl ? Xlo : Xhi) + (size_t)(m0 + srow) * DIN;
    const ushort_t* Wp = (spl ? Wl : Wh);

    for (int ks = 0; ks < 24; ++ks) {
        const int g  = ks >> 1;
        const int i0 = (ks & 1) * 32;
        int gp = g - hg; if (gp < 0) gp += NG;
        const uint4* pa = (const uint4*)(Xp + ks * 32);
        const uint4* pb = (const uint4*)(Wp + ((size_t)gp * 256 + o0 + srow) * 64 + i0);
        uint4 a0 = pa[0], a1 = pa[1], a2 = pa[2], a3 = pa[3];
        uint4 b0 = pb[0], b1 = pb[1], b2 = pb[2], b3 = pb[3];
        __syncthreads();
        *(uint4*)&As[spl][srow][0]  = a0;
        *(uint4*)&As[spl][srow][8]  = a1;
        *(uint4*)&As[spl][srow][16] = a2;
        *(uint4*)&As[spl][srow][24] = a3;
        *(uint4*)&Bs[spl][srow][0]  = b0;
        *(uint4*)&Bs[spl][srow][8]  = b1;
        *(uint4*)&Bs[spl][srow][16] = b2;
        *(uint4*)&Bs[spl][srow][24] = b3;
        __syncthreads();

        bf16x8 ah[4], al[4], bh[4], bl[4];
        #pragma unroll
        for (int t = 0; t < 4; ++t) {
            ah[t] = *(const bf16x8*)&As[0][wm + t * 16 + lm][lq * 8];
            al[t] = *(const bf16x8*)&As[1][wm + t * 16 + lm][lq * 8];
            bh[t] = *(const bf16x8*)&Bs[0][wn + t * 16 + lm][lq * 8];
            bl[t] = *(const bf16x8*)&Bs[1][wn + t * 16 + lm][lq * 8];
        }
        #pragma unroll
        for (int mt = 0; mt < 4; ++mt)
            #pragma unroll
            for (int nt = 0; nt < 4; ++nt) {
                acc[mt][nt] = __builtin_amdgcn_mfma_f32_16x16x32_bf16(ah[mt], bh[nt], acc[mt][nt], 0, 0, 0);
                acc[mt][nt] = __builtin_amdgcn_mfma_f32_16x16x32_bf16(ah[mt], bl[nt], acc[mt][nt], 0, 0, 0);
                acc[mt][nt] = __builtin_amdgcn_mfma_f32_16x16x32_bf16(al[mt], bh[nt], acc[mt][nt], 0, 0, 0);
            }
    }
    #pragma unroll
    for (int mt = 0; mt < 4; ++mt)
        #pragma unroll
        for (int r = 0; r < 4; ++r) {
            float* dst = out + (size_t)(m0 + wm + mt * 16 + lq * 4 + r) * DQK + c0 + wn + lm;
            #pragma unroll
            for (int nt = 0; nt < 4; ++nt) dst[nt * 16] = acc[mt][nt][r];
        }
}

// ---------------------------------------------------------------------------
// Kernel 2: RMSNorm + fused sequence-rope + platonic-rope (unchanged).
// ---------------------------------------------------------------------------
__global__ __launch_bounds__(256) void norm_rope_kernel(
    float* __restrict__ q, float* __restrict__ k,
    const float* __restrict__ coords,
    const int* __restrict__ seq,
    const float* __restrict__ qw,
    const float* __restrict__ kw,
    const float* __restrict__ pf)
{
    const int hid = blockIdx.x * 256 + threadIdx.x;
    const int gh = hid % GHH;
    const int bn = hid / GHH;
    const int g = gh >> 3;
    const int h = gh & 7;
    float* qp = q + (size_t)hid * CQK;
    float* kp = k + (size_t)hid * CQK;
    float xq[CQK], xk[CQK];
    #pragma unroll
    for (int u = 0; u < 8; ++u) *(float4*)(xq + 4 * u) = *(const float4*)(qp + 4 * u);
    #pragma unroll
    for (int u = 0; u < 8; ++u) *(float4*)(xk + 4 * u) = *(const float4*)(kp + 4 * u);

    float sq = 0.f, sk = 0.f;
    #pragma unroll
    for (int c = 0; c < CQK; ++c) { sq = fmaf(xq[c], xq[c], sq); sk = fmaf(xk[c], xk[c], sk); }
    const float eps = 1.1920928955078125e-07f;
    const float invq = rsqrtf(sq * (1.f / CQK) + eps);
    const float invk = rsqrtf(sk * (1.f / CQK) + eps);
    #pragma unroll
    for (int c = 0; c < CQK; ++c) { xq[c] *= invq * qw[c]; xk[c] *= invk * kw[c]; }

    const float pos = (float)seq[bn];
    const float cx = coords[bn * 3 + 0], cy = coords[bn * 3 + 1], cz = coords[bn * 3 + 2];
    float sg, cg;
    sincosf((float)g * 0.5235987755982988f, &sg, &cg);
    const float u0 = cg * cx + sg * cy;
    const float u1 = cg * cy - sg * cx;
    const float u2 = cz;

    #pragma unroll
    for (int f = 0; f < 16; ++f) {
        const float invf = exp2f(-(float)f * 0.8304820237218405f);
        const float* fr = pf + ((size_t)h * 16 + f) * 3;
        const float ang = fmaf(pos, invf, u0 * fr[0] + u1 * fr[1] + u2 * fr[2]);
        float sn, cs;
        sincosf(ang, &sn, &cs);
        float a1 = xq[2 * f], a2 = xq[2 * f + 1];
        xq[2 * f]     = a1 * cs - a2 * sn;
        xq[2 * f + 1] = a1 * sn + a2 * cs;
        float b1 = xk[2 * f], b2 = xk[2 * f + 1];
        xk[2 * f]     = b1 * cs - b2 * sn;
        xk[2 * f + 1] = b1 * sn + b2 * cs;
    }
    #pragma unroll
    for (int u = 0; u < 8; ++u) *(float4*)(qp + 4 * u) = *(const float4*)(xq + 4 * u);
    #pragma unroll
    for (int u = 0; u < 8; ++u) *(float4*)(kp + 4 * u) = *(const float4*)(xk + 4 * u);
}

// ---------------------------------------------------------------------------
// Kernel 3 (REWRITTEN): MFMA flash attention.
// Block = 4 waves, 128 q-rows (wave owns 32 = 2 m-tiles). Grid = (96,4,2).
// K/V staged per 128-key block, fp32 -> split-bf16 in-kernel.
// QK^T: 3 MFMAs (Qh*Kh + Qh*Kl + Ql*Kh) -> fp32-grade scores.
// Online softmax on C-layout tiles; P (bf16) through LDS into A-frag layout;
// PV: split V (2 MFMAs). V staged transposed [vdim][key] for B-frag reads.
// ---------------------------------------------------------------------------
__global__ __launch_bounds__(256, 1) void attn_mfma_kernel(
    const float* __restrict__ q,
    const float* __restrict__ k,
    const float* __restrict__ v,
    float* __restrict__ out)
{
    __shared__ __attribute__((aligned(16))) ushort_t Kh[128][40];
    __shared__ __attribute__((aligned(16))) ushort_t Kl[128][40];
    __shared__ __attribute__((aligned(16))) ushort_t Vth[32][136];
    __shared__ __attribute__((aligned(16))) ushort_t Vtl[32][136];
    __shared__ __attribute__((aligned(16))) ushort_t Ps[128][136];

    const int gh    = blockIdx.x;
    const int chunk = blockIdx.y;
    const int b     = blockIdx.z;
    const size_t headoff = (size_t)b * NN * DQK + (size_t)gh * CQK;
    const int tid  = threadIdx.x;
    const int lane = tid & 63;
    const int w    = tid >> 6;
    const int lm   = lane & 15;
    const int lq   = lane >> 4;       // quad
    const int qloc = w * 32;          // wave's local q-row base (0..96)

    // ---- load + scale + split Q fragments (A-layout: m=lm, k=lq*8+j) ----
    const float scale = 0.17677669529663687f;  // 1/sqrt(32)
    bf16x8 qh[2], ql[2];
    #pragma unroll
    for (int mt = 0; mt < 2; ++mt) {
        const int row = chunk * 128 + qloc + mt * 16 + lm;
        const float* qp = q + headoff + (size_t)row * DQK + lq * 8;
        float4 t0 = *(const float4*)qp;
        float4 t1 = *(const float4*)(qp + 4);
        float vals[8] = {t0.x, t0.y, t0.z, t0.w, t1.x, t1.y, t1.z, t1.w};
        short h8[8], l8[8];
        #pragma unroll
        for (int j = 0; j < 8; ++j) {
            float x = vals[j] * scale;
            ushort_t hb = bf16_rne(x);
            float hf = __uint_as_float(((unsigned)hb) << 16);
            h8[j] = (short)hb;
            l8[j] = (short)bf16_rne(x - hf);
        }
        qh[mt] = *(bf16x8*)h8;
        ql[mt] = *(bf16x8*)l8;
    }

    float mrun[2][4], lrun[2][4];
    f32x4 o[2][2];
    #pragma unroll
    for (int mt = 0; mt < 2; ++mt) {
        #pragma unroll
        for (int r = 0; r < 4; ++r) { mrun[mt][r] = -3.0e38f; lrun[mt][r] = 0.f; }
        o[mt][0] = (f32x4)(0.0f); o[mt][1] = (f32x4)(0.0f);
    }

    const int sr = tid >> 1;          // staging row 0..127
    const int sh = (tid & 1) * 16;    // staging col half

    for (int j0 = 0; j0 < NN; j0 += 128) {
        // ---- stage K (row-major, split) and V (transposed, split) ----
        const float* kp = k + headoff + (size_t)(j0 + sr) * DQK + sh;
        const float* vp = v + headoff + (size_t)(j0 + sr) * DQK + sh;
        float kb[16], vb[16];
        #pragma unroll
        for (int u = 0; u < 4; ++u) *(float4*)(kb + 4 * u) = *(const float4*)(kp + 4 * u);
        #pragma unroll
        for (int u = 0; u < 4; ++u) *(float4*)(vb + 4 * u) = *(const float4*)(vp + 4 * u);
        __syncthreads();   // previous iteration's PV reads done
        ushort_t kh16[16] __attribute__((aligned(16)));
        ushort_t kl16[16] __attribute__((aligned(16)));
        #pragma unroll
        for (int i = 0; i < 16; ++i) {
            ushort_t hb = bf16_rne(kb[i]);
            float hf = __uint_as_float(((unsigned)hb) << 16);
            kh16[i] = hb;
            kl16[i] = bf16_rne(kb[i] - hf);
            ushort_t vh = bf16_rne(vb[i]);
            float vf = __uint_as_float(((unsigned)vh) << 16);
            Vth[sh + i][sr] = vh;
            Vtl[sh + i][sr] = bf16_rne(vb[i] - vf);
        }
        *(uint4*)&Kh[sr][sh]     = *(uint4*)&kh16[0];
        *(uint4*)&Kh[sr][sh + 8] = *(uint4*)&kh16[8];
        *(uint4*)&Kl[sr][sh]     = *(uint4*)&kl16[0];
        *(uint4*)&Kl[sr][sh + 8] = *(uint4*)&kl16[8];
        __syncthreads();

        // ---- S = Q K^T for 128 keys (8 n-tiles) ----
        f32x4 sf[2][8];
        #pragma unroll
        for (int nt = 0; nt < 8; ++nt) {
            bf16x8 bh = *(const bf16x8*)&Kh[nt * 16 + lm][lq * 8];
            bf16x8 bl = *(const bf16x8*)&Kl[nt * 16 + lm][lq * 8];
            #pragma unroll
            for (int mt = 0; mt < 2; ++mt) {
                f32x4 s = (f32x4)(0.0f);
                s = __builtin_amdgcn_mfma_f32_16x16x32_bf16(qh[mt], bh, s, 0, 0, 0);
                s = __builtin_amdgcn_mfma_f32_16x16x32_bf16(qh[mt], bl, s, 0, 0, 0);
                s = __builtin_amdgcn_mfma_f32_16x16x32_bf16(ql[mt], bh, s, 0, 0, 0);
                sf[mt][nt] = s;
            }
        }

        // ---- online softmax: row stats, rescale O, write P (bf16) to LDS ----
        #pragma unroll
        for (int mt = 0; mt < 2; ++mt) {
            float cr[4];
            #pragma unroll
            for (int r = 0; r < 4; ++r) {
                float t = sf[mt][0][r];
                #pragma unroll
                for (int nt = 1; nt < 8; ++nt) t = fmaxf(t, sf[mt][nt][r]);
                t = fmaxf(t, __shfl_xor(t, 1, 64));
                t = fmaxf(t, __shfl_xor(t, 2, 64));
                t = fmaxf(t, __shfl_xor(t, 4, 64));
                t = fmaxf(t, __shfl_xor(t, 8, 64));
                const float mn = fmaxf(mrun[mt][r], t);
                cr[r] = __expf(mrun[mt][r] - mn);
                mrun[mt][r] = mn;
                lrun[mt][r] *= cr[r];
            }
            o[mt][0] *= f32x4{cr[0], cr[1], cr[2], cr[3]};
            o[mt][1] *= f32x4{cr[0], cr[1], cr[2], cr[3]};
            float rsum[4] = {0.f, 0.f, 0.f, 0.f};
            #pragma unroll
            for (int nt = 0; nt < 8; ++nt) {
                #pragma unroll
                for (int r = 0; r < 4; ++r) {
                    const float p = __expf(sf[mt][nt][r] - mrun[mt][r]);
                    rsum[r] += p;
                    Ps[qloc + mt * 16 + lq * 4 + r][nt * 16 + lm] = bf16_rne(p);
                }
            }
            #pragma unroll
            for (int r = 0; r < 4; ++r) {
                float t = rsum[r];
                t += __shfl_xor(t, 1, 64);
                t += __shfl_xor(t, 2, 64);
                t += __shfl_xor(t, 4, 64);
                t += __shfl_xor(t, 8, 64);
                lrun[mt][r] += t;
            }
        }
        __syncthreads();   // Ps + Vt visible for PV reads

        // ---- O += P V (A=P from LDS A-layout, B=Vt split) ----
        #pragma unroll
        for (int kt = 0; kt < 4; ++kt) {
            bf16x8 pa[2];
            #pragma unroll
            for (int mt = 0; mt < 2; ++mt)
                pa[mt] = *(const bf16x8*)&Ps[qloc + mt * 16 + lm][kt * 32 + lq * 8];
            #pragma unroll
            for (int vt = 0; vt < 2; ++vt) {
                bf16x8 bvh = *(const bf16x8*)&Vth[vt * 16 + lm][kt * 32 + lq * 8];
                bf16x8 bvl = *(const bf16x8*)&Vtl[vt * 16 + lm][kt * 32 + lq * 8];
                #pragma unroll
                for (int mt = 0; mt < 2; ++mt) {
                    o[mt][vt] = __builtin_amdgcn_mfma_f32_16x16x32_bf16(pa[mt], bvh, o[mt][vt], 0, 0, 0);
                    o[mt][vt] = __builtin_amdgcn_mfma_f32_16x16x32_bf16(pa[mt], bvl, o[mt][vt], 0, 0, 0);
                }
            }
        }
    }

    // ---- epilogue: normalize + store (C-layout row=lq*4+r, col=lm) ----
    #pragma unroll
    for (int mt = 0; mt < 2; ++mt) {
        float inv[4];
        #pragma unroll
        for (int r = 0; r < 4; ++r) inv[r] = 1.f / lrun[mt][r];
        #pragma unroll
        for (int r = 0; r < 4; ++r) {
            const int row = chunk * 128 + qloc + mt * 16 + lq * 4 + r;
            float* dst = out + headoff + (size_t)row * DQK + lm;
            dst[0]  = o[mt][0][r] * inv[r];
            dst[16] = o[mt][1][r] * inv[r];
        }
    }
}

// ---------------------------------------------------------------------------
// Kernel 4: output projection, split-bf16 MFMA with split-K=4 (unchanged).
// ---------------------------------------------------------------------------
__global__ __launch_bounds__(256, 1) void oproj_mfma_kernel(
    const ushort_t* __restrict__ Ahi, const ushort_t* __restrict__ Alo,   // [1024][3072]
    const ushort_t* __restrict__ Wohi, const ushort_t* __restrict__ Wolo, // [12][64][256]
    float* __restrict__ part)                                             // [4][1024][768]
{
    __shared__ __attribute__((aligned(16))) ushort_t As[2][128][40];
    __shared__ __attribute__((aligned(16))) ushort_t Bs[2][64][40];
    const int h  = blockIdx.x;
    const int m0 = blockIdx.y * 128;
    const int kz = blockIdx.z;
    const int tid  = threadIdx.x;
    const int srow = tid & 127;
    const int spl  = tid >> 7;
    const int lane = tid & 63;
    const int w    = tid >> 6;
    const int wm   = (w >> 1) * 64;
    const int wn   = (w & 1) * 32;
    const int lm   = lane & 15;
    const int lq   = lane >> 4;

    f32x4 acc[4][2];
    #pragma unroll
    for (int i = 0; i < 4; ++i) { acc[i][0] = (f32x4)(0.0f); acc[i][1] = (f32x4)(0.0f); }

    const ushort_t* Ap = (spl ? Alo : Ahi) + (size_t)(m0 + srow) * DQK;
    const int brow = tid & 63;
    const int bpl  = (tid >> 6) & 1;
    const ushort_t* Wp = (bpl ? Wolo : Wohi);

    for (int ks = 0; ks < 24; ++ks) {
        const int kk = kz * 768 + ks * 32;
        const int g  = kk >> 8;
        const int il = kk & 255;
        int gp = g - h; if (gp < 0) gp += NG;
        const uint4* pa = (const uint4*)(Ap + kk);
        uint4 a0 = pa[0], a1 = pa[1], a2 = pa[2], a3 = pa[3];
        uint4 b0, b1, b2, b3;
        if (tid < 128) {
            const uint4* pb = (const uint4*)(Wp + ((size_t)gp * 64 + brow) * 256 + il);
            b0 = pb[0]; b1 = pb[1]; b2 = pb[2]; b3 = pb[3];
        }
        __syncthreads();
        *(uint4*)&As[spl][srow][0]  = a0;
        *(uint4*)&As[spl][srow][8]  = a1;
        *(uint4*)&As[spl][srow][16] = a2;
        *(uint4*)&As[spl][srow][24] = a3;
        if (tid < 128) {
            *(uint4*)&Bs[bpl][brow][0]  = b0;
            *(uint4*)&Bs[bpl][brow][8]  = b1;
            *(uint4*)&Bs[bpl][brow][16] = b2;
            *(uint4*)&Bs[bpl][brow][24] = b3;
        }
        __syncthreads();

        bf16x8 ah[4], al[4], bh[2], bl[2];
        #pragma unroll
        for (int t = 0; t < 4; ++t) {
            ah[t] = *(const bf16x8*)&As[0][wm + t * 16 + lm][lq * 8];
            al[t] = *(const bf16x8*)&As[1][wm + t * 16 + lm][lq * 8];
        }
        #pragma unroll
        for (int t = 0; t < 2; ++t) {
            bh[t] = *(const bf16x8*)&Bs[0][wn + t * 16 + lm][lq * 8];
            bl[t] = *(const bf16x8*)&Bs[1][wn + t * 16 + lm][lq * 8];
        }
        #pragma unroll
        for (int mt = 0; mt < 4; ++mt)
            #pragma unroll
            for (int nt = 0; nt < 2; ++nt) {
                acc[mt][nt] = __builtin_amdgcn_mfma_f32_16x16x32_bf16(ah[mt], bh[nt], acc[mt][nt], 0, 0, 0);
                acc[mt][nt] = __builtin_amdgcn_mfma_f32_16x16x32_bf16(ah[mt], bl[nt], acc[mt][nt], 0, 0, 0);
                acc[mt][nt] = __builtin_amdgcn_mfma_f32_16x16x32_bf16(al[mt], bh[nt], acc[mt][nt], 0, 0, 0);
            }
    }
    float* dst0 = part + (size_t)kz * (NROWS * DOUT);
    #pragma unroll
    for (int mt = 0; mt < 4; ++mt)
        #pragma unroll
        for (int r = 0; r < 4; ++r) {
            float* dst = dst0 + (size_t)(m0 + wm + mt * 16 + lq * 4 + r) * DOUT + h * 64 + wn + lm;
            dst[0]  = acc[mt][0][r];
            dst[16] = acc[mt][1][r];
        }
}

__global__ __launch_bounds__(256) void reduce4_kernel(
    const float* __restrict__ part, float* __restrict__ out)
{
    const int i = blockIdx.x * 256 + threadIdx.x;   // over 196608 float4s
    const float4* p = (const float4*)part;
    const int s = NROWS * DOUT / 4;                 // 196608
    float4 a = p[i], b = p[i + s], c = p[i + 2 * s], d = p[i + 3 * s];
    ((float4*)out)[i] = make_float4(a.x + b.x + c.x + d.x, a.y + b.y + c.y + d.y,
                                    a.z + b.z + c.z + d.z, a.w + b.w + c.w + d.w);
}

// ---------------------------------------------------------------------------
extern "C" void kernel_launch(void* const* d_in, const int* in_sizes, int n_in,
                              void* d_out, int out_size, void* d_ws, size_t ws_size,
                              hipStream_t stream)
{
    const float* feat   = (const float*)d_in[0];
    const float* coords = (const float*)d_in[1];
    const float* Wq     = (const float*)d_in[2];
    const float* Wk     = (const float*)d_in[3];
    const float* Wv     = (const float*)d_in[4];
    const float* Wo     = (const float*)d_in[5];
    const float* qw     = (const float*)d_in[6];
    const float* kw     = (const float*)d_in[7];
    const float* pf     = (const float*)d_in[8];
    const int*   seq    = (const int*)d_in[9];

    const size_t SZ = (size_t)NROWS * DQK;          // 3145728 floats
    float* q  = (float*)d_ws;
    float* k  = q + SZ;
    float* v  = k + SZ;
    float* ao = v + SZ;

    // bf16 hi/lo planes for x + Wqkv live in the (currently dead) ao region
    ushort_t* Xhi  = (ushort_t*)ao;
    ushort_t* Xlo  = Xhi + (size_t)NROWS * DIN;              // 786432
    ushort_t* Wqh  = Xlo + (size_t)NROWS * DIN;
    ushort_t* Wql  = Wqh + (size_t)3 * NG * 256 * 64;        // 589824
    // after attention: ao splits into q region, Wo splits into v region,
    // oproj partials into k region (all dead by then)
    ushort_t* AOhi = (ushort_t*)q;
    ushort_t* AOlo = AOhi + SZ;
    ushort_t* WOhi = (ushort_t*)v;
    ushort_t* WOlo = WOhi + (size_t)NG * COUT * 256;         // 196608
    float*    part = k;                                      // 4 x 786432 floats

    const int NW = NG * 256 * 64;                            // 196608 per matrix

    split_kernel<<<dim3(768),  256, 0, stream>>>(feat, Xhi, Xlo, (NROWS * DIN) / 4);
    split_kernel<<<dim3(192),  256, 0, stream>>>(Wq, Wqh,          Wql,          NW / 4);
    split_kernel<<<dim3(192),  256, 0, stream>>>(Wk, Wqh + NW,     Wql + NW,     NW / 4);
    split_kernel<<<dim3(192),  256, 0, stream>>>(Wv, Wqh + 2 * NW, Wql + 2 * NW, NW / 4);

    qkv_mfma_kernel<<<dim3(24, 8, 3), 256, 0, stream>>>(Xhi, Xlo, Wqh, Wql, q, k, v);
    norm_rope_kernel<<<dim3(384), 256, 0, stream>>>(q, k, coords, seq, qw, kw, pf);
    attn_mfma_kernel<<<dim3(96, 4, 2), 256, 0, stream>>>(q, k, v, ao);

    split_kernel<<<dim3(192),  256, 0, stream>>>(Wo, WOhi, WOlo, (NG * COUT * 256) / 4);
    split_kernel<<<dim3(3072), 256, 0, stream>>>(ao, AOhi, AOlo, (int)(SZ / 4));
    oproj_mfma_kernel<<<dim3(12, 8, 4), 256, 0, stream>>>(AOhi, AOlo, WOhi, WOlo, part);
    reduce4_kernel<<<dim3(768), 256, 0, stream>>>(part, (float*)d_out);
}